// Round 2
// baseline (201.049 us; speedup 1.0000x reference)
//
#include <hip/hip_runtime.h>

#define NQ 4096
#define NS 2048
#define DD 1024
#define HH 3
#define PP 256
#define CC 100

typedef __attribute__((ext_vector_type(8))) short bf16x8;
typedef __attribute__((ext_vector_type(4))) float f32x4;

#define AS1 __attribute__((address_space(1)))
#define AS3 __attribute__((address_space(3)))

__device__ __forceinline__ void gload16(const void* g, void* l) {
  __builtin_amdgcn_global_load_lds((const AS1 unsigned int*)g,
                                   (AS3 unsigned int*)l, 16, 0, 0);
}

__device__ __forceinline__ unsigned short f2bf(float f) {
  union { float f; unsigned u; } v; v.f = f;
  return (unsigned short)((v.u + 0x7FFFu + ((v.u >> 16) & 1u)) >> 16);
}

// ---------------------------------------------------------------------------
// prep: blocks 0..1023    query mean -> Xq bf16
//       blocks 1024..1535 support cast -> Xs bf16
//       blocks 1536..1727 head_W transpose tiles -> Wt[h][p][k]
//       blocks 1728..1759 cls_W transpose tiles -> WcT[p][k] (pad to 128 rows)
// ---------------------------------------------------------------------------
__global__ __launch_bounds__(256) void prep_kernel(
    const float* __restrict__ q,      // [4][4096][1024]
    const float* __restrict__ sup,    // [2048][1024]
    const float* __restrict__ hW,     // [3][1024][256]
    const float* __restrict__ cW,     // [1024][100]
    unsigned short* __restrict__ Xq,  // [4096][1024]
    unsigned short* __restrict__ Xs,  // [2048][1024]
    unsigned short* __restrict__ Wt,  // [3][256][1024]
    unsigned short* __restrict__ WcT) // [128][1024]
{
  __shared__ unsigned short T[64][72];   // +8 pad: 2-way max bank aliasing
  const int b = blockIdx.x, t = threadIdx.x;

  if (b < 1536) {
    if (b < 1024) {
      #pragma unroll
      for (int i = 0; i < 4; ++i) {
        int idx = (b * 1024 + i * 256 + t) * 4;
        const float4 a  = *(const float4*)&q[idx];
        const float4 c1 = *(const float4*)&q[NQ * DD + idx];
        const float4 c2 = *(const float4*)&q[2 * NQ * DD + idx];
        const float4 c3 = *(const float4*)&q[3 * NQ * DD + idx];
        ushort4 o;
        o.x = f2bf((a.x + c1.x + c2.x + c3.x) * 0.25f);
        o.y = f2bf((a.y + c1.y + c2.y + c3.y) * 0.25f);
        o.z = f2bf((a.z + c1.z + c2.z + c3.z) * 0.25f);
        o.w = f2bf((a.w + c1.w + c2.w + c3.w) * 0.25f);
        *(ushort4*)&Xq[idx] = o;
      }
    } else {
      #pragma unroll
      for (int i = 0; i < 4; ++i) {
        int idx = ((b - 1024) * 1024 + i * 256 + t) * 4;
        const float4 a = *(const float4*)&sup[idx];
        ushort4 o;
        o.x = f2bf(a.x); o.y = f2bf(a.y); o.z = f2bf(a.z); o.w = f2bf(a.w);
        *(ushort4*)&Xs[idx] = o;
      }
    }
    return;
  }

  // ---- 64x64 transpose tile via LDS ----
  const float* src; unsigned short* dst; int srcC, pvalid, k0, p0;
  if (b < 1728) {
    int r = b - 1536; int h = r / 64; int rr = r % 64;
    k0 = (rr >> 2) * 64; p0 = (rr & 3) * 64;
    src = hW + h * DD * PP; srcC = PP; pvalid = PP;
    dst = Wt + (h * PP + p0) * DD;
  } else {
    int r = b - 1728;
    k0 = (r >> 1) * 64; p0 = (r & 1) * 64;
    src = cW; srcC = CC; pvalid = CC;
    dst = WcT + p0 * DD;
  }
  {
    int kl = t >> 2, pb = (t & 3) * 4;
    #pragma unroll
    for (int j = 0; j < 4; ++j) {
      int pl = pb + j * 16;
      int p = p0 + pl;
      float4 v; v.x = v.y = v.z = v.w = 0.f;
      if (p + 3 < pvalid) {
        v = *(const float4*)&src[(k0 + kl) * srcC + p];
      } else {
        if (p + 0 < pvalid) v.x = src[(k0 + kl) * srcC + p + 0];
        if (p + 1 < pvalid) v.y = src[(k0 + kl) * srcC + p + 1];
        if (p + 2 < pvalid) v.z = src[(k0 + kl) * srcC + p + 2];
        if (p + 3 < pvalid) v.w = src[(k0 + kl) * srcC + p + 3];
      }
      T[kl][pl + 0] = f2bf(v.x); T[kl][pl + 1] = f2bf(v.y);
      T[kl][pl + 2] = f2bf(v.z); T[kl][pl + 3] = f2bf(v.w);
    }
    __syncthreads();
    int pr = t >> 2, kb = (t & 3) * 4;
    #pragma unroll
    for (int j = 0; j < 4; ++j) {
      int kk = kb + j * 16;
      ushort4 o;
      o.x = T[kk + 0][pr]; o.y = T[kk + 1][pr];
      o.z = T[kk + 2][pr]; o.w = T[kk + 3][pr];
      *(ushort4*)&dst[pr * DD + k0 + kk] = o;
    }
  }
}

// ---------------------------------------------------------------------------
// proj: per head h: C = X @ Wt[h]^T + b[h], row-l2-normalize, bf16 out.
//       BM=64, BN=256(=P), BK=64, 4 waves, 2-phase double-buffered staging.
//       Qn rows pre-scaled by 1/3 (head-mean folded in).
// ---------------------------------------------------------------------------
__global__ __launch_bounds__(256) void proj_kernel(
    const unsigned short* __restrict__ Xq,
    const unsigned short* __restrict__ Xs,
    const unsigned short* __restrict__ Wt,
    const float* __restrict__ hb,      // [3][256]
    unsigned short* __restrict__ Qn,   // [4096][768]
    unsigned short* __restrict__ Sn)   // [2048][768]
{
  __shared__ unsigned short As[2][64 * 64];    // 16 KiB
  __shared__ unsigned short Bs[2][256 * 64];   // 64 KiB

  const int bid0 = blockIdx.x;
  const int bid = (bid0 & 7) * 36 + (bid0 >> 3);   // XCD chunk swizzle (288 = 8*36)
  const int h = bid / 96;
  const int r = bid % 96;
  const unsigned short* src; unsigned short* dst; int row0; float scale;
  if (r < 64) { src = Xq; dst = Qn; row0 = r * 64; scale = 1.f / 3.f; }
  else        { src = Xs; dst = Sn; row0 = (r - 64) * 64; scale = 1.f; }

  const int tid = threadIdx.x;
  const int w = tid >> 6, l = tid & 63;
  const int rA = l & 15, kg = l >> 4;
  const unsigned short* wbase = Wt + h * PP * DD;

  auto STAGE = [&](int buf, int kt) {
    #pragma unroll
    for (int i = 0; i < 10; ++i) {
      int c = w + i * 4;
      if (c < 8)
        gload16(src + (row0 + c * 8 + (l >> 3)) * DD + kt * 64 + (l & 7) * 8,
                &As[buf][c * 512]);
      else
        gload16(wbase + ((c - 8) * 8 + (l >> 3)) * DD + kt * 64 + (l & 7) * 8,
                &Bs[buf][(c - 8) * 512]);
    }
  };

  f32x4 acc[4][4] = {};
  STAGE(0, 0);
  __syncthreads();
  int cur = 0;
  for (int kt = 0; kt < DD / 64; ++kt) {
    if (kt + 1 < DD / 64) STAGE(cur ^ 1, kt + 1);
    #pragma unroll
    for (int kk = 0; kk < 2; ++kk) {
      bf16x8 a[4], bfr[4];
      #pragma unroll
      for (int mi = 0; mi < 4; ++mi)
        a[mi] = *(const bf16x8*)&As[cur][(mi * 16 + rA) * 64 + kk * 32 + kg * 8];
      #pragma unroll
      for (int ni = 0; ni < 4; ++ni)
        bfr[ni] = *(const bf16x8*)&Bs[cur][(w * 64 + ni * 16 + rA) * 64 + kk * 32 + kg * 8];
      #pragma unroll
      for (int mi = 0; mi < 4; ++mi)
        #pragma unroll
        for (int ni = 0; ni < 4; ++ni)
          acc[mi][ni] =
              __builtin_amdgcn_mfma_f32_16x16x32_bf16(a[mi], bfr[ni], acc[mi][ni], 0, 0, 0);
    }
    __syncthreads();
    cur ^= 1;
  }

  // epilogue: bias + row sum-of-squares; reuse As[0] as the reduction buffer
  float* rowsq = (float*)&As[0][0];   // [4][64]
  float bias[4];
  #pragma unroll
  for (int ni = 0; ni < 4; ++ni)
    bias[ni] = hb[h * PP + w * 64 + ni * 16 + rA];

  #pragma unroll
  for (int mi = 0; mi < 4; ++mi) {
    #pragma unroll
    for (int i = 0; i < 4; ++i) {
      float s = 0.f;
      #pragma unroll
      for (int ni = 0; ni < 4; ++ni) {
        float v = acc[mi][ni][i] + bias[ni];
        acc[mi][ni][i] = v;
        s += v * v;
      }
      s += __shfl_xor(s, 1);
      s += __shfl_xor(s, 2);
      s += __shfl_xor(s, 4);
      s += __shfl_xor(s, 8);
      if (rA == 0) rowsq[w * 64 + mi * 16 + kg * 4 + i] = s;
    }
  }
  __syncthreads();
  #pragma unroll
  for (int mi = 0; mi < 4; ++mi) {
    #pragma unroll
    for (int i = 0; i < 4; ++i) {
      int row = mi * 16 + kg * 4 + i;
      float tot = rowsq[row] + rowsq[64 + row] + rowsq[128 + row] + rowsq[192 + row];
      float inv = scale / fmaxf(sqrtf(tot), 1e-8f);
      #pragma unroll
      for (int ni = 0; ni < 4; ++ni) {
        int col = h * PP + w * 64 + ni * 16 + rA;
        dst[(row0 + row) * (HH * PP) + col] = f2bf(acc[mi][ni][i] * inv);
      }
    }
  }
}

// ---------------------------------------------------------------------------
// mm: blocks 0..511   match_scores = Qn @ Sn^T  [4096][2048] f32 (1/3 folded)
//     blocks 512..527 support_preds = Xs @ WcT^T + b [2048][100] f32
//     BM=BN=128, BK=64, 4 waves (2x2), 2-phase double-buffered staging.
// ---------------------------------------------------------------------------
__global__ __launch_bounds__(256) void mm_kernel(
    const unsigned short* __restrict__ Qn,
    const unsigned short* __restrict__ Sn,
    const unsigned short* __restrict__ Xs,
    const unsigned short* __restrict__ WcT,
    const float* __restrict__ cb,
    float* __restrict__ out)
{
  __shared__ unsigned short As[2][128 * 64];   // 32 KiB
  __shared__ unsigned short Bs[2][128 * 64];   // 32 KiB

  const int bid = blockIdx.x;
  const int tid = threadIdx.x;
  const int w = tid >> 6, l = tid & 63;
  const int wm = w >> 1, wn = w & 1;
  const int rA = l & 15, kg = l >> 4;

  const unsigned short *A, *B;
  int ldk, nkt, bm, bn;
  const bool match = bid < 512;
  if (match) {
    int sw = (bid & 7) * 64 + (bid >> 3);   // XCD chunk swizzle (512 = 8*64)
    bm = sw & 31; bn = sw >> 5;
    A = Qn + bm * 128 * (HH * PP);
    B = Sn + bn * 128 * (HH * PP);
    ldk = HH * PP; nkt = (HH * PP) / 64;
  } else {
    bm = bid - 512; bn = 0;
    A = Xs + bm * 128 * DD;
    B = WcT;
    ldk = DD; nkt = DD / 64;
  }

  auto STAGE = [&](int buf, int kt) {
    #pragma unroll
    for (int i = 0; i < 8; ++i) {
      int c = w + i * 4;
      if (c < 16)
        gload16(A + (c * 8 + (l >> 3)) * ldk + kt * 64 + (l & 7) * 8,
                &As[buf][c * 512]);
      else
        gload16(B + ((c - 16) * 8 + (l >> 3)) * ldk + kt * 64 + (l & 7) * 8,
                &Bs[buf][(c - 16) * 512]);
    }
  };

  f32x4 acc[4][4] = {};
  STAGE(0, 0);
  __syncthreads();
  int cur = 0;
  for (int kt = 0; kt < nkt; ++kt) {
    if (kt + 1 < nkt) STAGE(cur ^ 1, kt + 1);
    #pragma unroll
    for (int kk = 0; kk < 2; ++kk) {
      bf16x8 a[4], bfr[4];
      #pragma unroll
      for (int mi = 0; mi < 4; ++mi)
        a[mi] = *(const bf16x8*)&As[cur][(wm * 64 + mi * 16 + rA) * 64 + kk * 32 + kg * 8];
      #pragma unroll
      for (int ni = 0; ni < 4; ++ni)
        bfr[ni] = *(const bf16x8*)&Bs[cur][(wn * 64 + ni * 16 + rA) * 64 + kk * 32 + kg * 8];
      #pragma unroll
      for (int mi = 0; mi < 4; ++mi)
        #pragma unroll
        for (int ni = 0; ni < 4; ++ni)
          acc[mi][ni] =
              __builtin_amdgcn_mfma_f32_16x16x32_bf16(a[mi], bfr[ni], acc[mi][ni], 0, 0, 0);
    }
    __syncthreads();
    cur ^= 1;
  }

  if (match) {
    #pragma unroll
    for (int mi = 0; mi < 4; ++mi)
      #pragma unroll
      for (int i = 0; i < 4; ++i) {
        int row = bm * 128 + wm * 64 + mi * 16 + kg * 4 + i;
        #pragma unroll
        for (int ni = 0; ni < 4; ++ni) {
          int col = bn * 128 + wn * 64 + ni * 16 + rA;
          out[row * NS + col] = acc[mi][ni][i];
        }
      }
  } else {
    float* o2 = out + (long)NQ * NS;
    #pragma unroll
    for (int mi = 0; mi < 4; ++mi)
      #pragma unroll
      for (int i = 0; i < 4; ++i) {
        int row = bm * 128 + wm * 64 + mi * 16 + kg * 4 + i;
        #pragma unroll
        for (int ni = 0; ni < 4; ++ni) {
          int col = wn * 64 + ni * 16 + rA;
          if (col < CC) o2[row * CC + col] = acc[mi][ni][i] + cb[col];
        }
      }
  }
}

// ---------------------------------------------------------------------------
extern "C" void kernel_launch(void* const* d_in, const int* in_sizes, int n_in,
                              void* d_out, int out_size, void* d_ws, size_t ws_size,
                              hipStream_t stream) {
  const float* q   = (const float*)d_in[0];
  const float* sup = (const float*)d_in[1];
  const float* hW  = (const float*)d_in[2];
  const float* hb  = (const float*)d_in[3];
  const float* cW  = (const float*)d_in[4];
  const float* cb  = (const float*)d_in[5];
  float* out = (float*)d_out;

  char* ws = (char*)d_ws;
  unsigned short* Xq  = (unsigned short*)(ws + 0);                      // 8 MiB
  unsigned short* Xs  = (unsigned short*)(ws + (8u  << 20));            // 4 MiB
  unsigned short* Wt  = (unsigned short*)(ws + (12u << 20));            // 1.5 MiB
  unsigned short* WcT = (unsigned short*)(ws + (12u << 20) + 1572864u); // 256 KiB
  unsigned short* Qn  = (unsigned short*)(ws + (14u << 20));            // 6 MiB
  unsigned short* Sn  = (unsigned short*)(ws + (20u << 20));            // 3 MiB

  prep_kernel<<<1760, 256, 0, stream>>>(q, sup, hW, cW, Xq, Xs, Wt, WcT);
  proj_kernel<<<288, 256, 0, stream>>>(Xq, Xs, Wt, hb, Qn, Sn);
  mm_kernel<<<512 + 16, 256, 0, stream>>>(Qn, Sn, Xs, WcT, cb, out);
}

// Round 3
// 183.661 us; speedup vs baseline: 1.0947x; 1.0947x over previous
//
#include <hip/hip_runtime.h>

#define NQ 4096
#define NS 2048
#define DD 1024
#define HH 3
#define PP 256
#define CC 100

typedef __attribute__((ext_vector_type(8))) short bf16x8;
typedef __attribute__((ext_vector_type(4))) float f32x4;

#define AS1 __attribute__((address_space(1)))
#define AS3 __attribute__((address_space(3)))

__device__ __forceinline__ void gload16(const void* g, void* l) {
  __builtin_amdgcn_global_load_lds((const AS1 unsigned int*)g,
                                   (AS3 unsigned int*)l, 16, 0, 0);
}

__device__ __forceinline__ unsigned short f2bf(float f) {
  union { float f; unsigned u; } v; v.f = f;
  return (unsigned short)((v.u + 0x7FFFu + ((v.u >> 16) & 1u)) >> 16);
}

// ---------------------------------------------------------------------------
// prep: blocks 0..1023    query mean -> Xq bf16
//       blocks 1024..1535 support cast -> Xs bf16
//       blocks 1536..1727 head_W transpose tiles -> Wt[h][p][k]
//       blocks 1728..1759 cls_W transpose tiles -> WcT[p][k] (pad to 128 rows)
// ---------------------------------------------------------------------------
__global__ __launch_bounds__(256) void prep_kernel(
    const float* __restrict__ q,      // [4][4096][1024]
    const float* __restrict__ sup,    // [2048][1024]
    const float* __restrict__ hW,     // [3][1024][256]
    const float* __restrict__ cW,     // [1024][100]
    unsigned short* __restrict__ Xq,  // [4096][1024]
    unsigned short* __restrict__ Xs,  // [2048][1024]
    unsigned short* __restrict__ Wt,  // [3][256][1024]
    unsigned short* __restrict__ WcT) // [128][1024]
{
  __shared__ unsigned short T[64][72];
  const int b = blockIdx.x, t = threadIdx.x;

  if (b < 1536) {
    if (b < 1024) {
      #pragma unroll
      for (int i = 0; i < 4; ++i) {
        int idx = (b * 1024 + i * 256 + t) * 4;
        const float4 a  = *(const float4*)&q[idx];
        const float4 c1 = *(const float4*)&q[NQ * DD + idx];
        const float4 c2 = *(const float4*)&q[2 * NQ * DD + idx];
        const float4 c3 = *(const float4*)&q[3 * NQ * DD + idx];
        ushort4 o;
        o.x = f2bf((a.x + c1.x + c2.x + c3.x) * 0.25f);
        o.y = f2bf((a.y + c1.y + c2.y + c3.y) * 0.25f);
        o.z = f2bf((a.z + c1.z + c2.z + c3.z) * 0.25f);
        o.w = f2bf((a.w + c1.w + c2.w + c3.w) * 0.25f);
        *(ushort4*)&Xq[idx] = o;
      }
    } else {
      #pragma unroll
      for (int i = 0; i < 4; ++i) {
        int idx = ((b - 1024) * 1024 + i * 256 + t) * 4;
        const float4 a = *(const float4*)&sup[idx];
        ushort4 o;
        o.x = f2bf(a.x); o.y = f2bf(a.y); o.z = f2bf(a.z); o.w = f2bf(a.w);
        *(ushort4*)&Xs[idx] = o;
      }
    }
    return;
  }

  const float* src; unsigned short* dst; int srcC, pvalid, k0, p0;
  if (b < 1728) {
    int r = b - 1536; int h = r / 64; int rr = r % 64;
    k0 = (rr >> 2) * 64; p0 = (rr & 3) * 64;
    src = hW + h * DD * PP; srcC = PP; pvalid = PP;
    dst = Wt + (h * PP + p0) * DD;
  } else {
    int r = b - 1728;
    k0 = (r >> 1) * 64; p0 = (r & 1) * 64;
    src = cW; srcC = CC; pvalid = CC;
    dst = WcT + p0 * DD;
  }
  {
    int kl = t >> 2, pb = (t & 3) * 4;
    #pragma unroll
    for (int j = 0; j < 4; ++j) {
      int pl = pb + j * 16;
      int p = p0 + pl;
      float4 v; v.x = v.y = v.z = v.w = 0.f;
      if (p + 3 < pvalid) {
        v = *(const float4*)&src[(k0 + kl) * srcC + p];
      } else {
        if (p + 0 < pvalid) v.x = src[(k0 + kl) * srcC + p + 0];
        if (p + 1 < pvalid) v.y = src[(k0 + kl) * srcC + p + 1];
        if (p + 2 < pvalid) v.z = src[(k0 + kl) * srcC + p + 2];
        if (p + 3 < pvalid) v.w = src[(k0 + kl) * srcC + p + 3];
      }
      T[kl][pl + 0] = f2bf(v.x); T[kl][pl + 1] = f2bf(v.y);
      T[kl][pl + 2] = f2bf(v.z); T[kl][pl + 3] = f2bf(v.w);
    }
    __syncthreads();
    int pr = t >> 2, kb = (t & 3) * 4;
    #pragma unroll
    for (int j = 0; j < 4; ++j) {
      int kk = kb + j * 16;
      ushort4 o;
      o.x = T[kk + 0][pr]; o.y = T[kk + 1][pr];
      o.z = T[kk + 2][pr]; o.w = T[kk + 3][pr];
      *(ushort4*)&dst[pr * DD + k0 + kk] = o;
    }
  }
}

// ---------------------------------------------------------------------------
// proj: per head h: C = X @ Wt[h]^T + b[h], row-l2-normalize, bf16 out.
//       BM=64, BN=256(=P), BK=64, 4 waves, 2-phase dbuf, LDS-staged epilogue.
//       Qn rows pre-scaled by 1/3 (head-mean folded in).
// ---------------------------------------------------------------------------
__global__ __launch_bounds__(256) void proj_kernel(
    const unsigned short* __restrict__ Xq,
    const unsigned short* __restrict__ Xs,
    const unsigned short* __restrict__ Wt,
    const float* __restrict__ hb,      // [3][256]
    unsigned short* __restrict__ Qn,   // [4096][768]
    unsigned short* __restrict__ Sn)   // [2048][768]
{
  __shared__ unsigned short As[2][64 * 64];    // 16 KiB
  __shared__ unsigned short Bs[2][256 * 64];   // 64 KiB

  const int bid0 = blockIdx.x;
  const int bid = (bid0 & 7) * 36 + (bid0 >> 3);   // 288 = 8*36 bijective
  const int h = bid / 96;
  const int r = bid % 96;
  const unsigned short* src; unsigned short* dst; int row0; float scale;
  if (r < 64) { src = Xq; dst = Qn; row0 = r * 64; scale = 1.f / 3.f; }
  else        { src = Xs; dst = Sn; row0 = (r - 64) * 64; scale = 1.f; }

  const int tid = threadIdx.x;
  const int w = tid >> 6, l = tid & 63;
  const int rA = l & 15, kg = l >> 4;
  const unsigned short* wbase = Wt + h * PP * DD;

  auto STAGE = [&](int buf, int kt) {
    #pragma unroll
    for (int i = 0; i < 10; ++i) {
      int c = w + i * 4;
      if (c < 8)
        gload16(src + (row0 + c * 8 + (l >> 3)) * DD + kt * 64 + (l & 7) * 8,
                &As[buf][c * 512]);
      else
        gload16(wbase + ((c - 8) * 8 + (l >> 3)) * DD + kt * 64 + (l & 7) * 8,
                &Bs[buf][(c - 8) * 512]);
    }
  };

  f32x4 acc[4][4] = {};
  STAGE(0, 0);
  __syncthreads();
  int cur = 0;
  for (int kt = 0; kt < DD / 64; ++kt) {
    if (kt + 1 < DD / 64) STAGE(cur ^ 1, kt + 1);
    #pragma unroll
    for (int kk = 0; kk < 2; ++kk) {
      bf16x8 a[4], bfr[4];
      #pragma unroll
      for (int mi = 0; mi < 4; ++mi)
        a[mi] = *(const bf16x8*)&As[cur][(mi * 16 + rA) * 64 + kk * 32 + kg * 8];
      #pragma unroll
      for (int ni = 0; ni < 4; ++ni)
        bfr[ni] = *(const bf16x8*)&Bs[cur][(w * 64 + ni * 16 + rA) * 64 + kk * 32 + kg * 8];
      #pragma unroll
      for (int mi = 0; mi < 4; ++mi)
        #pragma unroll
        for (int ni = 0; ni < 4; ++ni)
          acc[mi][ni] =
              __builtin_amdgcn_mfma_f32_16x16x32_bf16(a[mi], bfr[ni], acc[mi][ni], 0, 0, 0);
    }
    __syncthreads();
    cur ^= 1;
  }

  // epilogue: bias + row sum-of-squares (rowsq in As), C tile in Bs, coalesced out
  float* rowsq = (float*)&As[0][0];           // [256] = [4 waves][64 rows]
  unsigned short* Ct = (unsigned short*)&Bs[0][0];  // [64][264] padded
  float bias[4];
  #pragma unroll
  for (int ni = 0; ni < 4; ++ni)
    bias[ni] = hb[h * PP + w * 64 + ni * 16 + rA];

  #pragma unroll
  for (int mi = 0; mi < 4; ++mi) {
    #pragma unroll
    for (int i = 0; i < 4; ++i) {
      float s = 0.f;
      #pragma unroll
      for (int ni = 0; ni < 4; ++ni) {
        float v = acc[mi][ni][i] + bias[ni];
        acc[mi][ni][i] = v;
        s += v * v;
      }
      s += __shfl_xor(s, 1);
      s += __shfl_xor(s, 2);
      s += __shfl_xor(s, 4);
      s += __shfl_xor(s, 8);
      if (rA == 0) rowsq[w * 64 + mi * 16 + kg * 4 + i] = s;
    }
  }
  __syncthreads();
  #pragma unroll
  for (int mi = 0; mi < 4; ++mi) {
    #pragma unroll
    for (int i = 0; i < 4; ++i) {
      int row = mi * 16 + kg * 4 + i;
      float tot = rowsq[row] + rowsq[64 + row] + rowsq[128 + row] + rowsq[192 + row];
      float inv = scale / fmaxf(sqrtf(tot), 1e-8f);
      #pragma unroll
      for (int ni = 0; ni < 4; ++ni)
        Ct[row * 264 + w * 64 + ni * 16 + rA] = f2bf(acc[mi][ni][i] * inv);
    }
  }
  __syncthreads();
  // coalesced store: 16 passes x 4 rows, ushort4 per lane (512B contiguous/row)
  #pragma unroll
  for (int pass = 0; pass < 16; ++pass) {
    int row = pass * 4 + (tid >> 6);
    int c = tid & 63;
    ushort4 o = *(const ushort4*)&Ct[row * 264 + c * 4];
    *(ushort4*)&dst[(row0 + row) * (HH * PP) + h * PP + c * 4] = o;
  }
}

// ---------------------------------------------------------------------------
// mm: blocks 0..511   match_scores = Qn @ Sn^T  [4096][2048] f32 (1/3 folded)
//     blocks 512..527 support_preds = Xs @ WcT^T + b [2048][100] f32
//     BM=BN=128, BK=64, 2-phase dbuf, LDS-staged f32x4 epilogue.
// ---------------------------------------------------------------------------
__global__ __launch_bounds__(256) void mm_kernel(
    const unsigned short* __restrict__ Qn,
    const unsigned short* __restrict__ Sn,
    const unsigned short* __restrict__ Xs,
    const unsigned short* __restrict__ WcT,
    const float* __restrict__ cb,
    float* __restrict__ out)
{
  // union: staging As[2](32K)+Bs[2](32K) = 64K ; epilogue Ct f32[128][132] = 66K
  __shared__ __align__(16) char smem[128 * 132 * 4];
  unsigned short* As = (unsigned short*)smem;            // [2][8192]
  unsigned short* Bs = (unsigned short*)(smem + 32768);  // [2][8192]
  float* Ct = (float*)smem;                              // [128][132]

  const int bid = blockIdx.x;
  const int tid = threadIdx.x;
  const int w = tid >> 6, l = tid & 63;
  const int wm = w >> 1, wn = w & 1;
  const int rA = l & 15, kg = l >> 4;

  const unsigned short *A, *B;
  int ldk, nkt, bm, bn;
  const bool match = bid < 512;
  if (match) {
    // XCD-chunk swizzle: xcd gets bm in [xcd*4, xcd*4+4) x all 16 bn  (~3.8MiB/L2)
    int xcd = bid & 7, idx = bid >> 3;
    bm = xcd * 4 + (idx & 3);
    bn = idx >> 2;
    A = Qn + bm * 128 * (HH * PP);
    B = Sn + bn * 128 * (HH * PP);
    ldk = HH * PP; nkt = (HH * PP) / 64;
  } else {
    bm = bid - 512; bn = 0;
    A = Xs + bm * 128 * DD;
    B = WcT;
    ldk = DD; nkt = DD / 64;
  }

  auto STAGE = [&](int buf, int kt) {
    #pragma unroll
    for (int i = 0; i < 8; ++i) {
      int c = w + i * 4;
      if (c < 16)
        gload16(A + (c * 8 + (l >> 3)) * ldk + kt * 64 + (l & 7) * 8,
                &As[buf * 8192 + c * 512]);
      else
        gload16(B + ((c - 16) * 8 + (l >> 3)) * ldk + kt * 64 + (l & 7) * 8,
                &Bs[buf * 8192 + (c - 16) * 512]);
    }
  };

  f32x4 acc[4][4] = {};
  STAGE(0, 0);
  __syncthreads();
  int cur = 0;
  for (int kt = 0; kt < nkt; ++kt) {
    if (kt + 1 < nkt) STAGE(cur ^ 1, kt + 1);
    #pragma unroll
    for (int kk = 0; kk < 2; ++kk) {
      bf16x8 a[4], bfr[4];
      #pragma unroll
      for (int mi = 0; mi < 4; ++mi)
        a[mi] = *(const bf16x8*)&As[cur * 8192 + (wm * 64 + mi * 16 + rA) * 64 + kk * 32 + kg * 8];
      #pragma unroll
      for (int ni = 0; ni < 4; ++ni)
        bfr[ni] = *(const bf16x8*)&Bs[cur * 8192 + (wn * 64 + ni * 16 + rA) * 64 + kk * 32 + kg * 8];
      #pragma unroll
      for (int mi = 0; mi < 4; ++mi)
        #pragma unroll
        for (int ni = 0; ni < 4; ++ni)
          acc[mi][ni] =
              __builtin_amdgcn_mfma_f32_16x16x32_bf16(a[mi], bfr[ni], acc[mi][ni], 0, 0, 0);
    }
    __syncthreads();
    cur ^= 1;
  }

  if (match) {
    // stage C tile into padded LDS, then fully-coalesced float4 stores
    #pragma unroll
    for (int mi = 0; mi < 4; ++mi)
      #pragma unroll
      for (int i = 0; i < 4; ++i) {
        int row = wm * 64 + mi * 16 + kg * 4 + i;
        #pragma unroll
        for (int ni = 0; ni < 4; ++ni)
          Ct[row * 132 + wn * 64 + ni * 16 + rA] = acc[mi][ni][i];
      }
    __syncthreads();
    #pragma unroll
    for (int pass = 0; pass < 16; ++pass) {
      int row = pass * 8 + (tid >> 5);
      int c = tid & 31;
      f32x4 v = *(const f32x4*)&Ct[row * 132 + c * 4];
      *(f32x4*)&out[(long)(bm * 128 + row) * NS + bn * 128 + c * 4] = v;
    }
  } else {
    float* o2 = out + (long)NQ * NS;
    #pragma unroll
    for (int mi = 0; mi < 4; ++mi)
      #pragma unroll
      for (int i = 0; i < 4; ++i) {
        int row = bm * 128 + wm * 64 + mi * 16 + kg * 4 + i;
        #pragma unroll
        for (int ni = 0; ni < 4; ++ni) {
          int col = wn * 64 + ni * 16 + rA;
          if (col < CC) o2[row * CC + col] = acc[mi][ni][i] + cb[col];
        }
      }
  }
}

// ---------------------------------------------------------------------------
extern "C" void kernel_launch(void* const* d_in, const int* in_sizes, int n_in,
                              void* d_out, int out_size, void* d_ws, size_t ws_size,
                              hipStream_t stream) {
  const float* q   = (const float*)d_in[0];
  const float* sup = (const float*)d_in[1];
  const float* hW  = (const float*)d_in[2];
  const float* hb  = (const float*)d_in[3];
  const float* cW  = (const float*)d_in[4];
  const float* cb  = (const float*)d_in[5];
  float* out = (float*)d_out;

  char* ws = (char*)d_ws;
  unsigned short* Xq  = (unsigned short*)(ws + 0);                      // 8 MiB
  unsigned short* Xs  = (unsigned short*)(ws + (8u  << 20));            // 4 MiB
  unsigned short* Wt  = (unsigned short*)(ws + (12u << 20));            // 1.5 MiB
  unsigned short* WcT = (unsigned short*)(ws + (12u << 20) + 1572864u); // 256 KiB
  unsigned short* Qn  = (unsigned short*)(ws + (14u << 20));            // 6 MiB
  unsigned short* Sn  = (unsigned short*)(ws + (20u << 20));            // 3 MiB

  prep_kernel<<<1760, 256, 0, stream>>>(q, sup, hW, cW, Xq, Xs, Wt, WcT);
  proj_kernel<<<288, 256, 0, stream>>>(Xq, Xs, Wt, hb, Qn, Sn);
  mm_kernel<<<512 + 16, 256, 0, stream>>>(Qn, Sn, Xs, WcT, cb, out);
}

// Round 4
// 181.652 us; speedup vs baseline: 1.1068x; 1.0111x over previous
//
#include <hip/hip_runtime.h>

#define NQ 4096
#define NS 2048
#define DD 1024
#define HH 3
#define PP 256
#define CC 100
#define NR (NQ + NS)        // 6144 projected rows
#define PN (HH * PP)        // 768 projected cols

typedef __attribute__((ext_vector_type(8))) short bf16x8;
typedef __attribute__((ext_vector_type(4))) float f32x4;

#define AS1 __attribute__((address_space(1)))
#define AS3 __attribute__((address_space(3)))

__device__ __forceinline__ void gload16(const void* g, void* l) {
  __builtin_amdgcn_global_load_lds((const AS1 unsigned int*)g,
                                   (AS3 unsigned int*)l, 16, 0, 0);
}

__device__ __forceinline__ unsigned short f2bf(float f) {
  union { float f; unsigned u; } v; v.f = f;
  return (unsigned short)((v.u + 0x7FFFu + ((v.u >> 16) & 1u)) >> 16);
}

__device__ __forceinline__ float bf2f(unsigned short s) {
  union { unsigned u; float f; } v; v.u = ((unsigned)s) << 16;
  return v.f;
}

// ---------------------------------------------------------------------------
// prep: blocks 0..1023    query mean -> Xq bf16
//       blocks 1024..1535 support cast -> Xs bf16 (contiguous after Xq)
//       blocks 1536..1727 head_W transpose tiles -> Wt[h][p][k]
//       blocks 1728..1759 cls_W transpose tiles -> WcT[p][k] (pad to 128 rows)
// ---------------------------------------------------------------------------
__global__ __launch_bounds__(256) void prep_kernel(
    const float* __restrict__ q,      // [4][4096][1024]
    const float* __restrict__ sup,    // [2048][1024]
    const float* __restrict__ hW,     // [3][1024][256]
    const float* __restrict__ cW,     // [1024][100]
    unsigned short* __restrict__ Xq,  // [4096][1024]
    unsigned short* __restrict__ Xs,  // [2048][1024]
    unsigned short* __restrict__ Wt,  // [3][256][1024]
    unsigned short* __restrict__ WcT) // [128][1024]
{
  __shared__ unsigned short T[64][72];
  const int b = blockIdx.x, t = threadIdx.x;

  if (b < 1536) {
    if (b < 1024) {
      #pragma unroll
      for (int i = 0; i < 4; ++i) {
        int idx = (b * 1024 + i * 256 + t) * 4;
        const float4 a  = *(const float4*)&q[idx];
        const float4 c1 = *(const float4*)&q[NQ * DD + idx];
        const float4 c2 = *(const float4*)&q[2 * NQ * DD + idx];
        const float4 c3 = *(const float4*)&q[3 * NQ * DD + idx];
        ushort4 o;
        o.x = f2bf((a.x + c1.x + c2.x + c3.x) * 0.25f);
        o.y = f2bf((a.y + c1.y + c2.y + c3.y) * 0.25f);
        o.z = f2bf((a.z + c1.z + c2.z + c3.z) * 0.25f);
        o.w = f2bf((a.w + c1.w + c2.w + c3.w) * 0.25f);
        *(ushort4*)&Xq[idx] = o;
      }
    } else {
      #pragma unroll
      for (int i = 0; i < 4; ++i) {
        int idx = ((b - 1024) * 1024 + i * 256 + t) * 4;
        const float4 a = *(const float4*)&sup[idx];
        ushort4 o;
        o.x = f2bf(a.x); o.y = f2bf(a.y); o.z = f2bf(a.z); o.w = f2bf(a.w);
        *(ushort4*)&Xs[idx] = o;
      }
    }
    return;
  }

  const float* src; unsigned short* dst; int srcC, pvalid, k0, p0;
  if (b < 1728) {
    int r = b - 1536; int h = r / 64; int rr = r % 64;
    k0 = (rr >> 2) * 64; p0 = (rr & 3) * 64;
    src = hW + h * DD * PP; srcC = PP; pvalid = PP;
    dst = Wt + (h * PP + p0) * DD;
  } else {
    int r = b - 1728;
    k0 = (r >> 1) * 64; p0 = (r & 1) * 64;
    src = cW; srcC = CC; pvalid = CC;
    dst = WcT + p0 * DD;
  }
  {
    int kl = t >> 2, pb = (t & 3) * 4;
    #pragma unroll
    for (int j = 0; j < 4; ++j) {
      int pl = pb + j * 16;
      int p = p0 + pl;
      float4 v; v.x = v.y = v.z = v.w = 0.f;
      if (p + 3 < pvalid) {
        v = *(const float4*)&src[(k0 + kl) * srcC + p];
      } else {
        if (p + 0 < pvalid) v.x = src[(k0 + kl) * srcC + p + 0];
        if (p + 1 < pvalid) v.y = src[(k0 + kl) * srcC + p + 1];
        if (p + 2 < pvalid) v.z = src[(k0 + kl) * srcC + p + 2];
        if (p + 3 < pvalid) v.w = src[(k0 + kl) * srcC + p + 3];
      }
      T[kl][pl + 0] = f2bf(v.x); T[kl][pl + 1] = f2bf(v.y);
      T[kl][pl + 2] = f2bf(v.z); T[kl][pl + 3] = f2bf(v.w);
    }
    __syncthreads();
    int pr = t >> 2, kb = (t & 3) * 4;
    #pragma unroll
    for (int j = 0; j < 4; ++j) {
      int kk = kb + j * 16;
      ushort4 o;
      o.x = T[kk + 0][pr]; o.y = T[kk + 1][pr];
      o.z = T[kk + 2][pr]; o.w = T[kk + 3][pr];
      *(ushort4*)&dst[pr * DD + k0 + kk] = o;
    }
  }
}

// ---------------------------------------------------------------------------
// pgemm: QS[6144][768] = bf16( X[6144][1024] @ Wall[768][1024]^T + b[768] )
//        128x128 tile, BK=64, 2-phase dbuf, LDS-staged coalesced bf16 stores.
//        XCD swizzle: each XCD gets 6 bm x 6 bn (A 1.5MB + B 1.5MB in L2).
// ---------------------------------------------------------------------------
__global__ __launch_bounds__(256) void pgemm_kernel(
    const unsigned short* __restrict__ X,    // [6144][1024]
    const unsigned short* __restrict__ Wall, // [768][1024]
    const float* __restrict__ ball,          // [768]
    unsigned short* __restrict__ QS)         // [6144][768]
{
  __shared__ __align__(16) char smem[65536];
  unsigned short* As = (unsigned short*)smem;            // [2][8192]
  unsigned short* Bs = (unsigned short*)(smem + 32768);  // [2][8192]
  unsigned short* Ct = (unsigned short*)smem;            // [128][136]

  const int bid = blockIdx.x;
  const int swz = (bid & 7) * 36 + (bid >> 3);   // 288 = 8*36, bijective
  const int bm = swz / 6, bn = swz % 6;
  const int tid = threadIdx.x;
  const int w = tid >> 6, l = tid & 63;
  const int wm = w >> 1, wn = w & 1;
  const int rA = l & 15, kg = l >> 4;

  const unsigned short* A = X + bm * 128 * DD;
  const unsigned short* B = Wall + bn * 128 * DD;

  auto STAGE = [&](int buf, int kt) {
    #pragma unroll
    for (int i = 0; i < 8; ++i) {
      int c = w + i * 4;
      if (c < 16)
        gload16(A + (c * 8 + (l >> 3)) * DD + kt * 64 + (l & 7) * 8,
                &As[buf * 8192 + c * 512]);
      else
        gload16(B + ((c - 16) * 8 + (l >> 3)) * DD + kt * 64 + (l & 7) * 8,
                &Bs[buf * 8192 + (c - 16) * 512]);
    }
  };

  f32x4 acc[4][4] = {};
  STAGE(0, 0);
  __syncthreads();
  int cur = 0;
  for (int kt = 0; kt < DD / 64; ++kt) {
    if (kt + 1 < DD / 64) STAGE(cur ^ 1, kt + 1);
    #pragma unroll
    for (int kk = 0; kk < 2; ++kk) {
      bf16x8 a[4], bfr[4];
      #pragma unroll
      for (int mi = 0; mi < 4; ++mi)
        a[mi] = *(const bf16x8*)&As[cur * 8192 + (wm * 64 + mi * 16 + rA) * 64 + kk * 32 + kg * 8];
      #pragma unroll
      for (int ni = 0; ni < 4; ++ni)
        bfr[ni] = *(const bf16x8*)&Bs[cur * 8192 + (wn * 64 + ni * 16 + rA) * 64 + kk * 32 + kg * 8];
      #pragma unroll
      for (int mi = 0; mi < 4; ++mi)
        #pragma unroll
        for (int ni = 0; ni < 4; ++ni)
          acc[mi][ni] =
              __builtin_amdgcn_mfma_f32_16x16x32_bf16(a[mi], bfr[ni], acc[mi][ni], 0, 0, 0);
    }
    __syncthreads();
    cur ^= 1;
  }

  float bias[4];
  #pragma unroll
  for (int ni = 0; ni < 4; ++ni)
    bias[ni] = ball[bn * 128 + wn * 64 + ni * 16 + rA];

  #pragma unroll
  for (int mi = 0; mi < 4; ++mi)
    #pragma unroll
    for (int i = 0; i < 4; ++i) {
      int row = wm * 64 + mi * 16 + kg * 4 + i;
      #pragma unroll
      for (int ni = 0; ni < 4; ++ni)
        Ct[row * 136 + wn * 64 + ni * 16 + rA] = f2bf(acc[mi][ni][i] + bias[ni]);
    }
  __syncthreads();
  #pragma unroll
  for (int pass = 0; pass < 16; ++pass) {
    int row = pass * 8 + (tid >> 5);
    int c = tid & 31;
    ushort4 v = *(const ushort4*)&Ct[row * 136 + c * 4];
    *(ushort4*)&QS[(bm * 128 + row) * PN + bn * 128 + c * 4] = v;
  }
}

// ---------------------------------------------------------------------------
// norm: in-place per-head-segment L2 normalize of QS rows; rows<4096 get 1/3.
//       1 wave per row; lane owns 4 cols of each 256-col head segment.
// ---------------------------------------------------------------------------
__global__ __launch_bounds__(256) void norm_kernel(
    unsigned short* __restrict__ QS)   // [6144][768]
{
  const int wid = blockIdx.x * 4 + (threadIdx.x >> 6);   // 0..6143
  const int l = threadIdx.x & 63;
  unsigned short* rowp = QS + wid * PN;
  const float scale = (wid < NQ) ? (1.f / 3.f) : 1.f;

  float v[3][4];
  float ss[3];
  #pragma unroll
  for (int h = 0; h < 3; ++h) {
    ushort4 u = *(const ushort4*)&rowp[h * PP + l * 4];
    v[h][0] = bf2f(u.x); v[h][1] = bf2f(u.y);
    v[h][2] = bf2f(u.z); v[h][3] = bf2f(u.w);
    ss[h] = v[h][0]*v[h][0] + v[h][1]*v[h][1] + v[h][2]*v[h][2] + v[h][3]*v[h][3];
  }
  #pragma unroll
  for (int s = 1; s < 64; s <<= 1) {
    ss[0] += __shfl_xor(ss[0], s);
    ss[1] += __shfl_xor(ss[1], s);
    ss[2] += __shfl_xor(ss[2], s);
  }
  #pragma unroll
  for (int h = 0; h < 3; ++h) {
    float inv = scale / fmaxf(sqrtf(ss[h]), 1e-8f);
    ushort4 o;
    o.x = f2bf(v[h][0] * inv); o.y = f2bf(v[h][1] * inv);
    o.z = f2bf(v[h][2] * inv); o.w = f2bf(v[h][3] * inv);
    *(ushort4*)&rowp[h * PP + l * 4] = o;
  }
}

// ---------------------------------------------------------------------------
// mm: blocks 0..511   match_scores = Qn @ Sn^T  [4096][2048] f32 (1/3 folded)
//     blocks 512..527 support_preds = Xs @ WcT^T + b [2048][100] f32
//     BM=BN=128, BK=64, 2-phase dbuf, LDS-staged f32x4 epilogue.
// ---------------------------------------------------------------------------
__global__ __launch_bounds__(256) void mm_kernel(
    const unsigned short* __restrict__ Qn,
    const unsigned short* __restrict__ Sn,
    const unsigned short* __restrict__ Xs,
    const unsigned short* __restrict__ WcT,
    const float* __restrict__ cb,
    float* __restrict__ out)
{
  __shared__ __align__(16) char smem[128 * 132 * 4];
  unsigned short* As = (unsigned short*)smem;            // [2][8192]
  unsigned short* Bs = (unsigned short*)(smem + 32768);  // [2][8192]
  float* Ct = (float*)smem;                              // [128][132]

  const int bid = blockIdx.x;
  const int tid = threadIdx.x;
  const int w = tid >> 6, l = tid & 63;
  const int wm = w >> 1, wn = w & 1;
  const int rA = l & 15, kg = l >> 4;

  const unsigned short *A, *B;
  int ldk, nkt, bm, bn;
  const bool match = bid < 512;
  if (match) {
    int xcd = bid & 7, idx = bid >> 3;
    bm = xcd * 4 + (idx & 3);
    bn = idx >> 2;
    A = Qn + bm * 128 * PN;
    B = Sn + bn * 128 * PN;
    ldk = PN; nkt = PN / 64;
  } else {
    bm = bid - 512; bn = 0;
    A = Xs + bm * 128 * DD;
    B = WcT;
    ldk = DD; nkt = DD / 64;
  }

  auto STAGE = [&](int buf, int kt) {
    #pragma unroll
    for (int i = 0; i < 8; ++i) {
      int c = w + i * 4;
      if (c < 16)
        gload16(A + (c * 8 + (l >> 3)) * ldk + kt * 64 + (l & 7) * 8,
                &As[buf * 8192 + c * 512]);
      else
        gload16(B + ((c - 16) * 8 + (l >> 3)) * ldk + kt * 64 + (l & 7) * 8,
                &Bs[buf * 8192 + (c - 16) * 512]);
    }
  };

  f32x4 acc[4][4] = {};
  STAGE(0, 0);
  __syncthreads();
  int cur = 0;
  for (int kt = 0; kt < nkt; ++kt) {
    if (kt + 1 < nkt) STAGE(cur ^ 1, kt + 1);
    #pragma unroll
    for (int kk = 0; kk < 2; ++kk) {
      bf16x8 a[4], bfr[4];
      #pragma unroll
      for (int mi = 0; mi < 4; ++mi)
        a[mi] = *(const bf16x8*)&As[cur * 8192 + (wm * 64 + mi * 16 + rA) * 64 + kk * 32 + kg * 8];
      #pragma unroll
      for (int ni = 0; ni < 4; ++ni)
        bfr[ni] = *(const bf16x8*)&Bs[cur * 8192 + (wn * 64 + ni * 16 + rA) * 64 + kk * 32 + kg * 8];
      #pragma unroll
      for (int mi = 0; mi < 4; ++mi)
        #pragma unroll
        for (int ni = 0; ni < 4; ++ni)
          acc[mi][ni] =
              __builtin_amdgcn_mfma_f32_16x16x32_bf16(a[mi], bfr[ni], acc[mi][ni], 0, 0, 0);
    }
    __syncthreads();
    cur ^= 1;
  }

  if (match) {
    #pragma unroll
    for (int mi = 0; mi < 4; ++mi)
      #pragma unroll
      for (int i = 0; i < 4; ++i) {
        int row = wm * 64 + mi * 16 + kg * 4 + i;
        #pragma unroll
        for (int ni = 0; ni < 4; ++ni)
          Ct[row * 132 + wn * 64 + ni * 16 + rA] = acc[mi][ni][i];
      }
    __syncthreads();
    #pragma unroll
    for (int pass = 0; pass < 16; ++pass) {
      int row = pass * 8 + (tid >> 5);
      int c = tid & 31;
      f32x4 v = *(const f32x4*)&Ct[row * 132 + c * 4];
      *(f32x4*)&out[(long)(bm * 128 + row) * NS + bn * 128 + c * 4] = v;
    }
  } else {
    float* o2 = out + (long)NQ * NS;
    #pragma unroll
    for (int mi = 0; mi < 4; ++mi)
      #pragma unroll
      for (int i = 0; i < 4; ++i) {
        int row = bm * 128 + wm * 64 + mi * 16 + kg * 4 + i;
        #pragma unroll
        for (int ni = 0; ni < 4; ++ni) {
          int col = wn * 64 + ni * 16 + rA;
          if (col < CC) o2[row * CC + col] = acc[mi][ni][i] + cb[col];
        }
      }
  }
}

// ---------------------------------------------------------------------------
extern "C" void kernel_launch(void* const* d_in, const int* in_sizes, int n_in,
                              void* d_out, int out_size, void* d_ws, size_t ws_size,
                              hipStream_t stream) {
  const float* q   = (const float*)d_in[0];
  const float* sup = (const float*)d_in[1];
  const float* hW  = (const float*)d_in[2];
  const float* hb  = (const float*)d_in[3];
  const float* cW  = (const float*)d_in[4];
  const float* cb  = (const float*)d_in[5];
  float* out = (float*)d_out;

  char* ws = (char*)d_ws;
  unsigned short* Xq  = (unsigned short*)(ws + 0);                      // 8 MiB  [4096][1024]
  unsigned short* Xs  = (unsigned short*)(ws + (8u  << 20));            // 4 MiB  [2048][1024] (contig after Xq)
  unsigned short* Wt  = (unsigned short*)(ws + (12u << 20));            // 1.5 MiB [768][1024]
  unsigned short* WcT = (unsigned short*)(ws + (12u << 20) + 1572864u); // 256 KiB [128][1024]
  unsigned short* QS  = (unsigned short*)(ws + (14u << 20));            // 9 MiB  [6144][768]
  unsigned short* Qn  = QS;                                             // rows 0..4095
  unsigned short* Sn  = QS + (size_t)NQ * PN;                           // rows 4096..6143

  prep_kernel<<<1760, 256, 0, stream>>>(q, sup, hW, cW, Xq, Xs, Wt, WcT);
  pgemm_kernel<<<288, 256, 0, stream>>>(Xq, Wt, hb, QS);
  norm_kernel<<<NR / 4, 256, 0, stream>>>(QS);
  mm_kernel<<<512 + 16, 256, 0, stream>>>(Qn, Sn, Xs, WcT, cb, out);
}

// Round 6
// 171.462 us; speedup vs baseline: 1.1726x; 1.0594x over previous
//
#include <hip/hip_runtime.h>

#define NQ 4096
#define NS 2048
#define DD 1024
#define HH 3
#define PP 256
#define CC 100
#define NR (NQ + NS)        // 6144 projected rows
#define PN (HH * PP)        // 768 projected cols

typedef __attribute__((ext_vector_type(8))) short bf16x8;
typedef __attribute__((ext_vector_type(4))) float f32x4;

#define AS1 __attribute__((address_space(1)))
#define AS3 __attribute__((address_space(3)))

#define S_WAIT_VM(n) asm volatile("s_waitcnt vmcnt(" #n ")" ::: "memory")
#define S_WAIT_LGKM0() asm volatile("s_waitcnt lgkmcnt(0)" ::: "memory")

__device__ __forceinline__ void gload16(const void* g, void* l) {
  __builtin_amdgcn_global_load_lds((const AS1 unsigned int*)g,
                                   (AS3 unsigned int*)l, 16, 0, 0);
}

__device__ __forceinline__ unsigned short f2bf(float f) {
  union { float f; unsigned u; } v; v.f = f;
  return (unsigned short)((v.u + 0x7FFFu + ((v.u >> 16) & 1u)) >> 16);
}

__device__ __forceinline__ float bf2f(unsigned short s) {
  union { unsigned u; float f; } v; v.u = ((unsigned)s) << 16;
  return v.f;
}

// ---------------------------------------------------------------------------
// prep (unchanged from R4)
// ---------------------------------------------------------------------------
__global__ __launch_bounds__(256) void prep_kernel(
    const float* __restrict__ q,      // [4][4096][1024]
    const float* __restrict__ sup,    // [2048][1024]
    const float* __restrict__ hW,     // [3][1024][256]
    const float* __restrict__ cW,     // [1024][100]
    unsigned short* __restrict__ Xq,  // [4096][1024]
    unsigned short* __restrict__ Xs,  // [2048][1024]
    unsigned short* __restrict__ Wt,  // [3][256][1024]
    unsigned short* __restrict__ WcT) // [128][1024]
{
  __shared__ unsigned short T[64][72];
  const int b = blockIdx.x, t = threadIdx.x;

  if (b < 1536) {
    if (b < 1024) {
      #pragma unroll
      for (int i = 0; i < 4; ++i) {
        int idx = (b * 1024 + i * 256 + t) * 4;
        const float4 a  = *(const float4*)&q[idx];
        const float4 c1 = *(const float4*)&q[NQ * DD + idx];
        const float4 c2 = *(const float4*)&q[2 * NQ * DD + idx];
        const float4 c3 = *(const float4*)&q[3 * NQ * DD + idx];
        ushort4 o;
        o.x = f2bf((a.x + c1.x + c2.x + c3.x) * 0.25f);
        o.y = f2bf((a.y + c1.y + c2.y + c3.y) * 0.25f);
        o.z = f2bf((a.z + c1.z + c2.z + c3.z) * 0.25f);
        o.w = f2bf((a.w + c1.w + c2.w + c3.w) * 0.25f);
        *(ushort4*)&Xq[idx] = o;
      }
    } else {
      #pragma unroll
      for (int i = 0; i < 4; ++i) {
        int idx = ((b - 1024) * 1024 + i * 256 + t) * 4;
        const float4 a = *(const float4*)&sup[idx];
        ushort4 o;
        o.x = f2bf(a.x); o.y = f2bf(a.y); o.z = f2bf(a.z); o.w = f2bf(a.w);
        *(ushort4*)&Xs[idx] = o;
      }
    }
    return;
  }

  const float* src; unsigned short* dst; int srcC, pvalid, k0, p0;
  if (b < 1728) {
    int r = b - 1536; int h = r / 64; int rr = r % 64;
    k0 = (rr >> 2) * 64; p0 = (rr & 3) * 64;
    src = hW + h * DD * PP; srcC = PP; pvalid = PP;
    dst = Wt + (h * PP + p0) * DD;
  } else {
    int r = b - 1728;
    k0 = (r >> 1) * 64; p0 = (r & 1) * 64;
    src = cW; srcC = CC; pvalid = CC;
    dst = WcT + p0 * DD;
  }
  {
    int kl = t >> 2, pb = (t & 3) * 4;
    #pragma unroll
    for (int j = 0; j < 4; ++j) {
      int pl = pb + j * 16;
      int p = p0 + pl;
      float4 v; v.x = v.y = v.z = v.w = 0.f;
      if (p + 3 < pvalid) {
        v = *(const float4*)&src[(k0 + kl) * srcC + p];
      } else {
        if (p + 0 < pvalid) v.x = src[(k0 + kl) * srcC + p + 0];
        if (p + 1 < pvalid) v.y = src[(k0 + kl) * srcC + p + 1];
        if (p + 2 < pvalid) v.z = src[(k0 + kl) * srcC + p + 2];
        if (p + 3 < pvalid) v.w = src[(k0 + kl) * srcC + p + 3];
      }
      T[kl][pl + 0] = f2bf(v.x); T[kl][pl + 1] = f2bf(v.y);
      T[kl][pl + 2] = f2bf(v.z); T[kl][pl + 3] = f2bf(v.w);
    }
    __syncthreads();
    int pr = t >> 2, kb = (t & 3) * 4;
    #pragma unroll
    for (int j = 0; j < 4; ++j) {
      int kk = kb + j * 16;
      ushort4 o;
      o.x = T[kk + 0][pr]; o.y = T[kk + 1][pr];
      o.z = T[kk + 2][pr]; o.w = T[kk + 3][pr];
      *(ushort4*)&dst[pr * DD + k0 + kk] = o;
    }
  }
}

// ---------------------------------------------------------------------------
// pgemm: QS[6144][768] = bf16( X @ Wall^T + b ).  128x128, BK=64.
//        T2 source-pre-swizzle + swizzled ds_read; counted-vmcnt pipeline.
// ---------------------------------------------------------------------------
__global__ __launch_bounds__(256) void pgemm_kernel(
    const unsigned short* __restrict__ X,    // [6144][1024]
    const unsigned short* __restrict__ Wall, // [768][1024]
    const float* __restrict__ ball,          // [768]
    unsigned short* __restrict__ QS)         // [6144][768]
{
  __shared__ __align__(16) char smem[65536];
  unsigned short* As = (unsigned short*)smem;            // [2][8192]
  unsigned short* Bs = (unsigned short*)(smem + 32768);  // [2][8192]
  unsigned short* Ct = (unsigned short*)smem;            // [128][136]

  const int bid = blockIdx.x;
  const int swz = (bid & 7) * 36 + (bid >> 3);   // 288 = 8*36, bijective
  const int bm = swz / 6, bn = swz % 6;
  const int tid = threadIdx.x;
  const int w = tid >> 6, l = tid & 63;
  const int wm = w >> 1, wn = w & 1;
  const int rA = l & 15, kg = l >> 4;
  const int xr = (rA & 7) << 3;                  // read-side XOR (ushorts)
  const int colsw = ((l & 7) * 8) ^ ((l >> 3) << 3);   // stage-side swizzled col

  const unsigned short* A = X + bm * 128 * DD;
  const unsigned short* B = Wall + bn * 128 * DD;

  auto STAGE = [&](int buf, int kt) {
    #pragma unroll
    for (int i = 0; i < 8; ++i) {
      int c = w + i * 4;
      if (c < 16)
        gload16(A + (c * 8 + (l >> 3)) * DD + kt * 64 + colsw,
                &As[buf * 8192 + c * 512]);
      else
        gload16(B + ((c - 16) * 8 + (l >> 3)) * DD + kt * 64 + colsw,
                &Bs[buf * 8192 + (c - 16) * 512]);
    }
  };

  f32x4 acc[4][4] = {};
  STAGE(0, 0);
  int cur = 0;
  for (int kt = 0; kt < DD / 64; ++kt) {
    if (kt + 1 < DD / 64) {
      STAGE(cur ^ 1, kt + 1);
      S_WAIT_VM(8);
    } else {
      S_WAIT_VM(0);
    }
    __builtin_amdgcn_sched_barrier(0);
    __builtin_amdgcn_s_barrier();
    #pragma unroll
    for (int kk = 0; kk < 2; ++kk) {
      bf16x8 a[4], bfr[4];
      #pragma unroll
      for (int mi = 0; mi < 4; ++mi)
        a[mi] = *(const bf16x8*)&As[cur * 8192 + (wm * 64 + mi * 16 + rA) * 64 +
                                    ((kk * 32 + kg * 8) ^ xr)];
      #pragma unroll
      for (int ni = 0; ni < 4; ++ni)
        bfr[ni] = *(const bf16x8*)&Bs[cur * 8192 + (wn * 64 + ni * 16 + rA) * 64 +
                                      ((kk * 32 + kg * 8) ^ xr)];
      #pragma unroll
      for (int mi = 0; mi < 4; ++mi)
        #pragma unroll
        for (int ni = 0; ni < 4; ++ni)
          acc[mi][ni] =
              __builtin_amdgcn_mfma_f32_16x16x32_bf16(a[mi], bfr[ni], acc[mi][ni], 0, 0, 0);
    }
    S_WAIT_LGKM0();
    __builtin_amdgcn_sched_barrier(0);
    __builtin_amdgcn_s_barrier();
    cur ^= 1;
  }

  float bias[4];
  #pragma unroll
  for (int ni = 0; ni < 4; ++ni)
    bias[ni] = ball[bn * 128 + wn * 64 + ni * 16 + rA];

  #pragma unroll
  for (int mi = 0; mi < 4; ++mi)
    #pragma unroll
    for (int i = 0; i < 4; ++i) {
      int row = wm * 64 + mi * 16 + kg * 4 + i;
      #pragma unroll
      for (int ni = 0; ni < 4; ++ni)
        Ct[row * 136 + wn * 64 + ni * 16 + rA] = f2bf(acc[mi][ni][i] + bias[ni]);
    }
  __syncthreads();
  #pragma unroll
  for (int pass = 0; pass < 16; ++pass) {
    int row = pass * 8 + (tid >> 5);
    int c = tid & 31;
    ushort4 v = *(const ushort4*)&Ct[row * 136 + c * 4];
    *(ushort4*)&QS[(bm * 128 + row) * PN + bn * 128 + c * 4] = v;
  }
}

// ---------------------------------------------------------------------------
// norm: in-place per-head-segment L2 normalize; rows<4096 get 1/3 folded.
// ---------------------------------------------------------------------------
__global__ __launch_bounds__(256) void norm_kernel(
    unsigned short* __restrict__ QS)   // [6144][768]
{
  const int wid = blockIdx.x * 4 + (threadIdx.x >> 6);
  const int l = threadIdx.x & 63;
  unsigned short* rowp = QS + wid * PN;
  const float scale = (wid < NQ) ? (1.f / 3.f) : 1.f;

  float v[3][4];
  float ss[3];
  #pragma unroll
  for (int h = 0; h < 3; ++h) {
    ushort4 u = *(const ushort4*)&rowp[h * PP + l * 4];
    v[h][0] = bf2f(u.x); v[h][1] = bf2f(u.y);
    v[h][2] = bf2f(u.z); v[h][3] = bf2f(u.w);
    ss[h] = v[h][0]*v[h][0] + v[h][1]*v[h][1] + v[h][2]*v[h][2] + v[h][3]*v[h][3];
  }
  #pragma unroll
  for (int s = 1; s < 64; s <<= 1) {
    ss[0] += __shfl_xor(ss[0], s);
    ss[1] += __shfl_xor(ss[1], s);
    ss[2] += __shfl_xor(ss[2], s);
  }
  #pragma unroll
  for (int h = 0; h < 3; ++h) {
    float inv = scale / fmaxf(sqrtf(ss[h]), 1e-8f);
    ushort4 o;
    o.x = f2bf(v[h][0] * inv); o.y = f2bf(v[h][1] * inv);
    o.z = f2bf(v[h][2] * inv); o.w = f2bf(v[h][3] * inv);
    *(ushort4*)&rowp[h * PP + l * 4] = o;
  }
}

// ---------------------------------------------------------------------------
// mm: blocks 0..511   match_scores = Qn @ Sn^T  [4096][2048] f32 (1/3 folded)
//     blocks 512..527 support_preds = Xs @ WcT^T + b [2048][100] f32
//     T2 swizzle + counted-vmcnt pipeline; LDS-staged f32x4 epilogue.
// ---------------------------------------------------------------------------
__global__ __launch_bounds__(256) void mm_kernel(
    const unsigned short* __restrict__ Qn,
    const unsigned short* __restrict__ Sn,
    const unsigned short* __restrict__ Xs,
    const unsigned short* __restrict__ WcT,
    const float* __restrict__ cb,
    float* __restrict__ out)
{
  __shared__ __align__(16) char smem[128 * 132 * 4];
  unsigned short* As = (unsigned short*)smem;            // [2][8192]
  unsigned short* Bs = (unsigned short*)(smem + 32768);  // [2][8192]
  float* Ct = (float*)smem;                              // [128][132]

  const int bid = blockIdx.x;
  const int tid = threadIdx.x;
  const int w = tid >> 6, l = tid & 63;
  const int wm = w >> 1, wn = w & 1;
  const int rA = l & 15, kg = l >> 4;
  const int xr = (rA & 7) << 3;
  const int colsw = ((l & 7) * 8) ^ ((l >> 3) << 3);

  const unsigned short *A, *B;
  int ldk, nkt, bm, bn;
  const bool match = bid < 512;
  if (match) {
    int xcd = bid & 7, idx = bid >> 3;
    bm = xcd * 4 + (idx & 3);
    bn = idx >> 2;
    A = Qn + bm * 128 * PN;
    B = Sn + bn * 128 * PN;
    ldk = PN; nkt = PN / 64;
  } else {
    bm = bid - 512; bn = 0;
    A = Xs + bm * 128 * DD;
    B = WcT;
    ldk = DD; nkt = DD / 64;
  }

  auto STAGE = [&](int buf, int kt) {
    #pragma unroll
    for (int i = 0; i < 8; ++i) {
      int c = w + i * 4;
      if (c < 16)
        gload16(A + (c * 8 + (l >> 3)) * ldk + kt * 64 + colsw,
                &As[buf * 8192 + c * 512]);
      else
        gload16(B + ((c - 16) * 8 + (l >> 3)) * ldk + kt * 64 + colsw,
                &Bs[buf * 8192 + (c - 16) * 512]);
    }
  };

  f32x4 acc[4][4] = {};
  STAGE(0, 0);
  int cur = 0;
  for (int kt = 0; kt < nkt; ++kt) {
    if (kt + 1 < nkt) {
      STAGE(cur ^ 1, kt + 1);
      S_WAIT_VM(8);
    } else {
      S_WAIT_VM(0);
    }
    __builtin_amdgcn_sched_barrier(0);
    __builtin_amdgcn_s_barrier();
    #pragma unroll
    for (int kk = 0; kk < 2; ++kk) {
      bf16x8 a[4], bfr[4];
      #pragma unroll
      for (int mi = 0; mi < 4; ++mi)
        a[mi] = *(const bf16x8*)&As[cur * 8192 + (wm * 64 + mi * 16 + rA) * 64 +
                                    ((kk * 32 + kg * 8) ^ xr)];
      #pragma unroll
      for (int ni = 0; ni < 4; ++ni)
        bfr[ni] = *(const bf16x8*)&Bs[cur * 8192 + (wn * 64 + ni * 16 + rA) * 64 +
                                      ((kk * 32 + kg * 8) ^ xr)];
      #pragma unroll
      for (int mi = 0; mi < 4; ++mi)
        #pragma unroll
        for (int ni = 0; ni < 4; ++ni)
          acc[mi][ni] =
              __builtin_amdgcn_mfma_f32_16x16x32_bf16(a[mi], bfr[ni], acc[mi][ni], 0, 0, 0);
    }
    S_WAIT_LGKM0();
    __builtin_amdgcn_sched_barrier(0);
    __builtin_amdgcn_s_barrier();
    cur ^= 1;
  }

  if (match) {
    #pragma unroll
    for (int mi = 0; mi < 4; ++mi)
      #pragma unroll
      for (int i = 0; i < 4; ++i) {
        int row = wm * 64 + mi * 16 + kg * 4 + i;
        #pragma unroll
        for (int ni = 0; ni < 4; ++ni)
          Ct[row * 132 + wn * 64 + ni * 16 + rA] = acc[mi][ni][i];
      }
    __syncthreads();
    #pragma unroll
    for (int pass = 0; pass < 16; ++pass) {
      int row = pass * 8 + (tid >> 5);
      int c = tid & 31;
      f32x4 v = *(const f32x4*)&Ct[row * 132 + c * 4];
      *(f32x4*)&out[(long)(bm * 128 + row) * NS + bn * 128 + c * 4] = v;
    }
  } else {
    float* o2 = out + (long)NQ * NS;
    #pragma unroll
    for (int mi = 0; mi < 4; ++mi)
      #pragma unroll
      for (int i = 0; i < 4; ++i) {
        int row = bm * 128 + wm * 64 + mi * 16 + kg * 4 + i;
        #pragma unroll
        for (int ni = 0; ni < 4; ++ni) {
          int col = wn * 64 + ni * 16 + rA;
          if (col < CC) o2[row * CC + col] = acc[mi][ni][i] + cb[col];
        }
      }
  }
}

// ---------------------------------------------------------------------------
extern "C" void kernel_launch(void* const* d_in, const int* in_sizes, int n_in,
                              void* d_out, int out_size, void* d_ws, size_t ws_size,
                              hipStream_t stream) {
  const float* q   = (const float*)d_in[0];
  const float* sup = (const float*)d_in[1];
  const float* hW  = (const float*)d_in[2];
  const float* hb  = (const float*)d_in[3];
  const float* cW  = (const float*)d_in[4];
  const float* cb  = (const float*)d_in[5];
  float* out = (float*)d_out;

  char* ws = (char*)d_ws;
  unsigned short* Xq  = (unsigned short*)(ws + 0);                      // 8 MiB  [4096][1024]
  unsigned short* Xs  = (unsigned short*)(ws + (8u  << 20));            // 4 MiB  [2048][1024]
  unsigned short* Wt  = (unsigned short*)(ws + (12u << 20));            // 1.5 MiB [768][1024]
  unsigned short* WcT = (unsigned short*)(ws + (12u << 20) + 1572864u); // 256 KiB [128][1024]
  unsigned short* QS  = (unsigned short*)(ws + (14u << 20));            // 9 MiB  [6144][768]
  unsigned short* Qn  = QS;
  unsigned short* Sn  = QS + (size_t)NQ * PN;

  prep_kernel<<<1760, 256, 0, stream>>>(q, sup, hW, cW, Xq, Xs, Wt, WcT);
  pgemm_kernel<<<288, 256, 0, stream>>>(Xq, Wt, hb, QS);
  norm_kernel<<<NR / 4, 256, 0, stream>>>(QS);
  mm_kernel<<<512 + 16, 256, 0, stream>>>(Qn, Sn, Xs, WcT, cb, out);
}

// Round 7
// 168.324 us; speedup vs baseline: 1.1944x; 1.0186x over previous
//
#include <hip/hip_runtime.h>

#define NQ 4096
#define NS 2048
#define DD 1024
#define HH 3
#define PP 256
#define CC 100
#define NR (NQ + NS)        // 6144 projected rows
#define PN (HH * PP)        // 768 projected cols

typedef __attribute__((ext_vector_type(8))) short bf16x8;
typedef __attribute__((ext_vector_type(4))) float f32x4;

#define AS1 __attribute__((address_space(1)))
#define AS3 __attribute__((address_space(3)))

#define S_WAIT_VM(n) asm volatile("s_waitcnt vmcnt(" #n ")" ::: "memory")
#define S_WAIT_LGKM0() asm volatile("s_waitcnt lgkmcnt(0)" ::: "memory")

__device__ __forceinline__ void gload16(const void* g, void* l) {
  __builtin_amdgcn_global_load_lds((const AS1 unsigned int*)g,
                                   (AS3 unsigned int*)l, 16, 0, 0);
}

__device__ __forceinline__ unsigned short f2bf(float f) {
  union { float f; unsigned u; } v; v.f = f;
  return (unsigned short)((v.u + 0x7FFFu + ((v.u >> 16) & 1u)) >> 16);
}

__device__ __forceinline__ float bf2f(unsigned short s) {
  union { unsigned u; float f; } v; v.u = ((unsigned)s) << 16;
  return v.f;
}

// ---------------------------------------------------------------------------
// prep (unchanged)
// ---------------------------------------------------------------------------
__global__ __launch_bounds__(256) void prep_kernel(
    const float* __restrict__ q,      // [4][4096][1024]
    const float* __restrict__ sup,    // [2048][1024]
    const float* __restrict__ hW,     // [3][1024][256]
    const float* __restrict__ cW,     // [1024][100]
    unsigned short* __restrict__ Xq,  // [4096][1024]
    unsigned short* __restrict__ Xs,  // [2048][1024]
    unsigned short* __restrict__ Wt,  // [3][256][1024]
    unsigned short* __restrict__ WcT) // [128][1024]
{
  __shared__ unsigned short T[64][72];
  const int b = blockIdx.x, t = threadIdx.x;

  if (b < 1536) {
    if (b < 1024) {
      #pragma unroll
      for (int i = 0; i < 4; ++i) {
        int idx = (b * 1024 + i * 256 + t) * 4;
        const float4 a  = *(const float4*)&q[idx];
        const float4 c1 = *(const float4*)&q[NQ * DD + idx];
        const float4 c2 = *(const float4*)&q[2 * NQ * DD + idx];
        const float4 c3 = *(const float4*)&q[3 * NQ * DD + idx];
        ushort4 o;
        o.x = f2bf((a.x + c1.x + c2.x + c3.x) * 0.25f);
        o.y = f2bf((a.y + c1.y + c2.y + c3.y) * 0.25f);
        o.z = f2bf((a.z + c1.z + c2.z + c3.z) * 0.25f);
        o.w = f2bf((a.w + c1.w + c2.w + c3.w) * 0.25f);
        *(ushort4*)&Xq[idx] = o;
      }
    } else {
      #pragma unroll
      for (int i = 0; i < 4; ++i) {
        int idx = ((b - 1024) * 1024 + i * 256 + t) * 4;
        const float4 a = *(const float4*)&sup[idx];
        ushort4 o;
        o.x = f2bf(a.x); o.y = f2bf(a.y); o.z = f2bf(a.z); o.w = f2bf(a.w);
        *(ushort4*)&Xs[idx] = o;
      }
    }
    return;
  }

  const float* src; unsigned short* dst; int srcC, pvalid, k0, p0;
  if (b < 1728) {
    int r = b - 1536; int h = r / 64; int rr = r % 64;
    k0 = (rr >> 2) * 64; p0 = (rr & 3) * 64;
    src = hW + h * DD * PP; srcC = PP; pvalid = PP;
    dst = Wt + (h * PP + p0) * DD;
  } else {
    int r = b - 1728;
    k0 = (r >> 1) * 64; p0 = (r & 1) * 64;
    src = cW; srcC = CC; pvalid = CC;
    dst = WcT + p0 * DD;
  }
  {
    int kl = t >> 2, pb = (t & 3) * 4;
    #pragma unroll
    for (int j = 0; j < 4; ++j) {
      int pl = pb + j * 16;
      int p = p0 + pl;
      float4 v; v.x = v.y = v.z = v.w = 0.f;
      if (p + 3 < pvalid) {
        v = *(const float4*)&src[(k0 + kl) * srcC + p];
      } else {
        if (p + 0 < pvalid) v.x = src[(k0 + kl) * srcC + p + 0];
        if (p + 1 < pvalid) v.y = src[(k0 + kl) * srcC + p + 1];
        if (p + 2 < pvalid) v.z = src[(k0 + kl) * srcC + p + 2];
        if (p + 3 < pvalid) v.w = src[(k0 + kl) * srcC + p + 3];
      }
      T[kl][pl + 0] = f2bf(v.x); T[kl][pl + 1] = f2bf(v.y);
      T[kl][pl + 2] = f2bf(v.z); T[kl][pl + 3] = f2bf(v.w);
    }
    __syncthreads();
    int pr = t >> 2, kb = (t & 3) * 4;
    #pragma unroll
    for (int j = 0; j < 4; ++j) {
      int kk = kb + j * 16;
      ushort4 o;
      o.x = T[kk + 0][pr]; o.y = T[kk + 1][pr];
      o.z = T[kk + 2][pr]; o.w = T[kk + 3][pr];
      *(ushort4*)&dst[pr * DD + k0 + kk] = o;
    }
  }
}

// ---------------------------------------------------------------------------
// pgemm: QS[6144][768] = bf16( X @ Wall^T + b ).  128x128, BK=64.
//        512 threads / 8 waves (2x4), wave tile 64x32.
//        T2 source-pre-swizzle + swizzled ds_read; counted-vmcnt pipeline.
// ---------------------------------------------------------------------------
__global__ __launch_bounds__(512) void pgemm_kernel(
    const unsigned short* __restrict__ X,    // [6144][1024]
    const unsigned short* __restrict__ Wall, // [768][1024]
    const float* __restrict__ ball,          // [768]
    unsigned short* __restrict__ QS)         // [6144][768]
{
  __shared__ __align__(16) char smem[65536];
  unsigned short* As = (unsigned short*)smem;            // [2][8192]
  unsigned short* Bs = (unsigned short*)(smem + 32768);  // [2][8192]
  unsigned short* Ct = (unsigned short*)smem;            // [128][136]

  const int bid = blockIdx.x;
  const int swz = (bid & 7) * 36 + (bid >> 3);   // 288 = 8*36, bijective
  const int bm = swz / 6, bn = swz % 6;
  const int tid = threadIdx.x;
  const int w = tid >> 6, l = tid & 63;
  const int wm = w >> 2, wn = w & 3;             // 2x4 wave grid
  const int rA = l & 15, kg = l >> 4;
  const int xr = (rA & 7) << 3;                  // read-side XOR (ushorts)
  const int colsw = ((l & 7) * 8) ^ ((l >> 3) << 3);   // stage-side swizzled col

  const unsigned short* A = X + bm * 128 * DD;
  const unsigned short* B = Wall + bn * 128 * DD;

  auto STAGE = [&](int buf, int kt) {
    #pragma unroll
    for (int p = 0; p < 2; ++p) {
      int row = p * 64 + w * 8 + (l >> 3);
      gload16(A + row * DD + kt * 64 + colsw,
              &As[buf * 8192 + (p * 64 + w * 8) * 64]);
    }
    #pragma unroll
    for (int p = 0; p < 2; ++p) {
      int row = p * 64 + w * 8 + (l >> 3);
      gload16(B + row * DD + kt * 64 + colsw,
              &Bs[buf * 8192 + (p * 64 + w * 8) * 64]);
    }
  };

  f32x4 acc[4][2] = {};
  STAGE(0, 0);
  int cur = 0;
  for (int kt = 0; kt < DD / 64; ++kt) {
    if (kt + 1 < DD / 64) {
      STAGE(cur ^ 1, kt + 1);
      S_WAIT_VM(4);
    } else {
      S_WAIT_VM(0);
    }
    __builtin_amdgcn_sched_barrier(0);
    __builtin_amdgcn_s_barrier();
    #pragma unroll
    for (int kk = 0; kk < 2; ++kk) {
      bf16x8 a[4], bfr[2];
      #pragma unroll
      for (int mi = 0; mi < 4; ++mi)
        a[mi] = *(const bf16x8*)&As[cur * 8192 + (wm * 64 + mi * 16 + rA) * 64 +
                                    ((kk * 32 + kg * 8) ^ xr)];
      #pragma unroll
      for (int ni = 0; ni < 2; ++ni)
        bfr[ni] = *(const bf16x8*)&Bs[cur * 8192 + (wn * 32 + ni * 16 + rA) * 64 +
                                      ((kk * 32 + kg * 8) ^ xr)];
      #pragma unroll
      for (int mi = 0; mi < 4; ++mi)
        #pragma unroll
        for (int ni = 0; ni < 2; ++ni)
          acc[mi][ni] =
              __builtin_amdgcn_mfma_f32_16x16x32_bf16(a[mi], bfr[ni], acc[mi][ni], 0, 0, 0);
    }
    S_WAIT_LGKM0();
    __builtin_amdgcn_sched_barrier(0);
    __builtin_amdgcn_s_barrier();
    cur ^= 1;
  }

  float bias[2];
  #pragma unroll
  for (int ni = 0; ni < 2; ++ni)
    bias[ni] = ball[bn * 128 + wn * 32 + ni * 16 + rA];

  #pragma unroll
  for (int mi = 0; mi < 4; ++mi)
    #pragma unroll
    for (int i = 0; i < 4; ++i) {
      int row = wm * 64 + mi * 16 + kg * 4 + i;
      #pragma unroll
      for (int ni = 0; ni < 2; ++ni)
        Ct[row * 136 + wn * 32 + ni * 16 + rA] = f2bf(acc[mi][ni][i] + bias[ni]);
    }
  __syncthreads();
  #pragma unroll
  for (int pass = 0; pass < 8; ++pass) {
    int row = pass * 16 + (tid >> 5);
    int c = tid & 31;
    ushort4 v = *(const ushort4*)&Ct[row * 136 + c * 4];
    *(ushort4*)&QS[(bm * 128 + row) * PN + bn * 128 + c * 4] = v;
  }
}

// ---------------------------------------------------------------------------
// norm: in-place per-head-segment L2 normalize; rows<4096 get 1/3 folded.
// ---------------------------------------------------------------------------
__global__ __launch_bounds__(256) void norm_kernel(
    unsigned short* __restrict__ QS)   // [6144][768]
{
  const int wid = blockIdx.x * 4 + (threadIdx.x >> 6);
  const int l = threadIdx.x & 63;
  unsigned short* rowp = QS + wid * PN;
  const float scale = (wid < NQ) ? (1.f / 3.f) : 1.f;

  float v[3][4];
  float ss[3];
  #pragma unroll
  for (int h = 0; h < 3; ++h) {
    ushort4 u = *(const ushort4*)&rowp[h * PP + l * 4];
    v[h][0] = bf2f(u.x); v[h][1] = bf2f(u.y);
    v[h][2] = bf2f(u.z); v[h][3] = bf2f(u.w);
    ss[h] = v[h][0]*v[h][0] + v[h][1]*v[h][1] + v[h][2]*v[h][2] + v[h][3]*v[h][3];
  }
  #pragma unroll
  for (int s = 1; s < 64; s <<= 1) {
    ss[0] += __shfl_xor(ss[0], s);
    ss[1] += __shfl_xor(ss[1], s);
    ss[2] += __shfl_xor(ss[2], s);
  }
  #pragma unroll
  for (int h = 0; h < 3; ++h) {
    float inv = scale / fmaxf(sqrtf(ss[h]), 1e-8f);
    ushort4 o;
    o.x = f2bf(v[h][0] * inv); o.y = f2bf(v[h][1] * inv);
    o.z = f2bf(v[h][2] * inv); o.w = f2bf(v[h][3] * inv);
    *(ushort4*)&rowp[h * PP + l * 4] = o;
  }
}

// ---------------------------------------------------------------------------
// mm: blocks 0..511   match_scores = Qn @ Sn^T  [4096][2048] f32 (1/3 folded)
//     blocks 512..527 support_preds = Xs @ WcT^T + b [2048][100] f32
//     512 threads / 8 waves (2x4), wave tile 64x32.
//     T2 swizzle + counted-vmcnt pipeline; LDS-staged f32x4 epilogue.
// ---------------------------------------------------------------------------
__global__ __launch_bounds__(512) void mm_kernel(
    const unsigned short* __restrict__ Qn,
    const unsigned short* __restrict__ Sn,
    const unsigned short* __restrict__ Xs,
    const unsigned short* __restrict__ WcT,
    const float* __restrict__ cb,
    float* __restrict__ out)
{
  __shared__ __align__(16) char smem[128 * 132 * 4];
  unsigned short* As = (unsigned short*)smem;            // [2][8192]
  unsigned short* Bs = (unsigned short*)(smem + 32768);  // [2][8192]
  float* Ct = (float*)smem;                              // [128][132]

  const int bid = blockIdx.x;
  const int tid = threadIdx.x;
  const int w = tid >> 6, l = tid & 63;
  const int wm = w >> 2, wn = w & 3;             // 2x4 wave grid
  const int rA = l & 15, kg = l >> 4;
  const int xr = (rA & 7) << 3;
  const int colsw = ((l & 7) * 8) ^ ((l >> 3) << 3);

  const unsigned short *A, *B;
  int ldk, nkt, bm, bn;
  const bool match = bid < 512;
  if (match) {
    int xcd = bid & 7, idx = bid >> 3;
    bm = xcd * 4 + (idx & 3);
    bn = idx >> 2;
    A = Qn + bm * 128 * PN;
    B = Sn + bn * 128 * PN;
    ldk = PN; nkt = PN / 64;
  } else {
    bm = bid - 512; bn = 0;
    A = Xs + bm * 128 * DD;
    B = WcT;
    ldk = DD; nkt = DD / 64;
  }

  auto STAGE = [&](int buf, int kt) {
    #pragma unroll
    for (int p = 0; p < 2; ++p) {
      int row = p * 64 + w * 8 + (l >> 3);
      gload16(A + row * ldk + kt * 64 + colsw,
              &As[buf * 8192 + (p * 64 + w * 8) * 64]);
    }
    #pragma unroll
    for (int p = 0; p < 2; ++p) {
      int row = p * 64 + w * 8 + (l >> 3);
      gload16(B + row * ldk + kt * 64 + colsw,
              &Bs[buf * 8192 + (p * 64 + w * 8) * 64]);
    }
  };

  f32x4 acc[4][2] = {};
  STAGE(0, 0);
  int cur = 0;
  for (int kt = 0; kt < nkt; ++kt) {
    if (kt + 1 < nkt) {
      STAGE(cur ^ 1, kt + 1);
      S_WAIT_VM(4);
    } else {
      S_WAIT_VM(0);
    }
    __builtin_amdgcn_sched_barrier(0);
    __builtin_amdgcn_s_barrier();
    #pragma unroll
    for (int kk = 0; kk < 2; ++kk) {
      bf16x8 a[4], bfr[2];
      #pragma unroll
      for (int mi = 0; mi < 4; ++mi)
        a[mi] = *(const bf16x8*)&As[cur * 8192 + (wm * 64 + mi * 16 + rA) * 64 +
                                    ((kk * 32 + kg * 8) ^ xr)];
      #pragma unroll
      for (int ni = 0; ni < 2; ++ni)
        bfr[ni] = *(const bf16x8*)&Bs[cur * 8192 + (wn * 32 + ni * 16 + rA) * 64 +
                                      ((kk * 32 + kg * 8) ^ xr)];
      #pragma unroll
      for (int mi = 0; mi < 4; ++mi)
        #pragma unroll
        for (int ni = 0; ni < 2; ++ni)
          acc[mi][ni] =
              __builtin_amdgcn_mfma_f32_16x16x32_bf16(a[mi], bfr[ni], acc[mi][ni], 0, 0, 0);
    }
    S_WAIT_LGKM0();
    __builtin_amdgcn_sched_barrier(0);
    __builtin_amdgcn_s_barrier();
    cur ^= 1;
  }

  if (match) {
    #pragma unroll
    for (int mi = 0; mi < 4; ++mi)
      #pragma unroll
      for (int i = 0; i < 4; ++i) {
        int row = wm * 64 + mi * 16 + kg * 4 + i;
        #pragma unroll
        for (int ni = 0; ni < 2; ++ni)
          Ct[row * 132 + wn * 32 + ni * 16 + rA] = acc[mi][ni][i];
      }
    __syncthreads();
    #pragma unroll
    for (int pass = 0; pass < 8; ++pass) {
      int row = pass * 16 + (tid >> 5);
      int c = tid & 31;
      f32x4 v = *(const f32x4*)&Ct[row * 132 + c * 4];
      *(f32x4*)&out[(long)(bm * 128 + row) * NS + bn * 128 + c * 4] = v;
    }
  } else {
    float* o2 = out + (long)NQ * NS;
    #pragma unroll
    for (int mi = 0; mi < 4; ++mi)
      #pragma unroll
      for (int i = 0; i < 4; ++i) {
        int row = bm * 128 + wm * 64 + mi * 16 + kg * 4 + i;
        #pragma unroll
        for (int ni = 0; ni < 2; ++ni) {
          int col = wn * 32 + ni * 16 + rA;
          if (col < CC) o2[row * CC + col] = acc[mi][ni][i] + cb[col];
        }
      }
  }
}

// ---------------------------------------------------------------------------
extern "C" void kernel_launch(void* const* d_in, const int* in_sizes, int n_in,
                              void* d_out, int out_size, void* d_ws, size_t ws_size,
                              hipStream_t stream) {
  const float* q   = (const float*)d_in[0];
  const float* sup = (const float*)d_in[1];
  const float* hW  = (const float*)d_in[2];
  const float* hb  = (const float*)d_in[3];
  const float* cW  = (const float*)d_in[4];
  const float* cb  = (const float*)d_in[5];
  float* out = (float*)d_out;

  char* ws = (char*)d_ws;
  unsigned short* Xq  = (unsigned short*)(ws + 0);                      // 8 MiB  [4096][1024]
  unsigned short* Xs  = (unsigned short*)(ws + (8u  << 20));            // 4 MiB  [2048][1024]
  unsigned short* Wt  = (unsigned short*)(ws + (12u << 20));            // 1.5 MiB [768][1024]
  unsigned short* WcT = (unsigned short*)(ws + (12u << 20) + 1572864u); // 256 KiB [128][1024]
  unsigned short* QS  = (unsigned short*)(ws + (14u << 20));            // 9 MiB  [6144][768]
  unsigned short* Qn  = QS;
  unsigned short* Sn  = QS + (size_t)NQ * PN;

  prep_kernel<<<1760, 256, 0, stream>>>(q, sup, hW, cW, Xq, Xs, Wt, WcT);
  pgemm_kernel<<<288, 512, 0, stream>>>(Xq, Wt, hb, QS);
  norm_kernel<<<NR / 4, 256, 0, stream>>>(QS);
  mm_kernel<<<512 + 16, 512, 0, stream>>>(Qn, Sn, Xs, WcT, cb, out);
}

// Round 8
// 161.163 us; speedup vs baseline: 1.2475x; 1.0444x over previous
//
#include <hip/hip_runtime.h>

#define NQ 4096
#define NS 2048
#define DD 1024
#define HH 3
#define PP 256
#define CC 100
#define NR (NQ + NS)        // 6144 projected rows
#define PN (HH * PP)        // 768 projected cols

typedef __attribute__((ext_vector_type(8))) short bf16x8;
typedef __attribute__((ext_vector_type(4))) float f32x4;

#define AS1 __attribute__((address_space(1)))
#define AS3 __attribute__((address_space(3)))

#define S_WAIT_VM(n) asm volatile("s_waitcnt vmcnt(" #n ")" ::: "memory")
#define S_WAIT_LGKM0() asm volatile("s_waitcnt lgkmcnt(0)" ::: "memory")

__device__ __forceinline__ void gload16(const void* g, void* l) {
  __builtin_amdgcn_global_load_lds((const AS1 unsigned int*)g,
                                   (AS3 unsigned int*)l, 16, 0, 0);
}

__device__ __forceinline__ unsigned short f2bf(float f) {
  union { float f; unsigned u; } v; v.f = f;
  return (unsigned short)((v.u + 0x7FFFu + ((v.u >> 16) & 1u)) >> 16);
}

__device__ __forceinline__ float bf2f(unsigned short s) {
  union { unsigned u; float f; } v; v.u = ((unsigned)s) << 16;
  return v.f;
}

// ---------------------------------------------------------------------------
// prep (unchanged)
// ---------------------------------------------------------------------------
__global__ __launch_bounds__(256) void prep_kernel(
    const float* __restrict__ q,      // [4][4096][1024]
    const float* __restrict__ sup,    // [2048][1024]
    const float* __restrict__ hW,     // [3][1024][256]
    const float* __restrict__ cW,     // [1024][100]
    unsigned short* __restrict__ Xq,  // [4096][1024]
    unsigned short* __restrict__ Xs,  // [2048][1024]
    unsigned short* __restrict__ Wt,  // [3][256][1024]
    unsigned short* __restrict__ WcT) // [128][1024]
{
  __shared__ unsigned short T[64][72];
  const int b = blockIdx.x, t = threadIdx.x;

  if (b < 1536) {
    if (b < 1024) {
      #pragma unroll
      for (int i = 0; i < 4; ++i) {
        int idx = (b * 1024 + i * 256 + t) * 4;
        const float4 a  = *(const float4*)&q[idx];
        const float4 c1 = *(const float4*)&q[NQ * DD + idx];
        const float4 c2 = *(const float4*)&q[2 * NQ * DD + idx];
        const float4 c3 = *(const float4*)&q[3 * NQ * DD + idx];
        ushort4 o;
        o.x = f2bf((a.x + c1.x + c2.x + c3.x) * 0.25f);
        o.y = f2bf((a.y + c1.y + c2.y + c3.y) * 0.25f);
        o.z = f2bf((a.z + c1.z + c2.z + c3.z) * 0.25f);
        o.w = f2bf((a.w + c1.w + c2.w + c3.w) * 0.25f);
        *(ushort4*)&Xq[idx] = o;
      }
    } else {
      #pragma unroll
      for (int i = 0; i < 4; ++i) {
        int idx = ((b - 1024) * 1024 + i * 256 + t) * 4;
        const float4 a = *(const float4*)&sup[idx];
        ushort4 o;
        o.x = f2bf(a.x); o.y = f2bf(a.y); o.z = f2bf(a.z); o.w = f2bf(a.w);
        *(ushort4*)&Xs[idx] = o;
      }
    }
    return;
  }

  const float* src; unsigned short* dst; int srcC, pvalid, k0, p0;
  if (b < 1728) {
    int r = b - 1536; int h = r / 64; int rr = r % 64;
    k0 = (rr >> 2) * 64; p0 = (rr & 3) * 64;
    src = hW + h * DD * PP; srcC = PP; pvalid = PP;
    dst = Wt + (h * PP + p0) * DD;
  } else {
    int r = b - 1728;
    k0 = (r >> 1) * 64; p0 = (r & 1) * 64;
    src = cW; srcC = CC; pvalid = CC;
    dst = WcT + p0 * DD;
  }
  {
    int kl = t >> 2, pb = (t & 3) * 4;
    #pragma unroll
    for (int j = 0; j < 4; ++j) {
      int pl = pb + j * 16;
      int p = p0 + pl;
      float4 v; v.x = v.y = v.z = v.w = 0.f;
      if (p + 3 < pvalid) {
        v = *(const float4*)&src[(k0 + kl) * srcC + p];
      } else {
        if (p + 0 < pvalid) v.x = src[(k0 + kl) * srcC + p + 0];
        if (p + 1 < pvalid) v.y = src[(k0 + kl) * srcC + p + 1];
        if (p + 2 < pvalid) v.z = src[(k0 + kl) * srcC + p + 2];
        if (p + 3 < pvalid) v.w = src[(k0 + kl) * srcC + p + 3];
      }
      T[kl][pl + 0] = f2bf(v.x); T[kl][pl + 1] = f2bf(v.y);
      T[kl][pl + 2] = f2bf(v.z); T[kl][pl + 3] = f2bf(v.w);
    }
    __syncthreads();
    int pr = t >> 2, kb = (t & 3) * 4;
    #pragma unroll
    for (int j = 0; j < 4; ++j) {
      int kk = kb + j * 16;
      ushort4 o;
      o.x = T[kk + 0][pr]; o.y = T[kk + 1][pr];
      o.z = T[kk + 2][pr]; o.w = T[kk + 3][pr];
      *(ushort4*)&dst[pr * DD + k0 + kk] = o;
    }
  }
}

// ---------------------------------------------------------------------------
// pgemm: blocks 0..287   QS[6144][768] = bf16( X @ Wall^T + b )
//        blocks 288..303 support_preds = Xs @ WcT^T + cb -> out (f32)
//        128x128, BK=64, 512 thr / 8 waves (2x4), T2 swizzle, counted vmcnt.
//        Both roles have K=1024 (16 K-steps): balanced, all 304 co-resident.
// ---------------------------------------------------------------------------
__global__ __launch_bounds__(512) void pgemm_kernel(
    const unsigned short* __restrict__ X,    // [6144][1024] (Xq||Xs)
    const unsigned short* __restrict__ Wall, // [768][1024]
    const float* __restrict__ ball,          // [768]
    const unsigned short* __restrict__ Xs,   // [2048][1024]
    const unsigned short* __restrict__ WcT,  // [128][1024]
    const float* __restrict__ cb,            // [100]
    unsigned short* __restrict__ QS,         // [6144][768]
    float* __restrict__ out)                 // preds at out + NQ*NS
{
  __shared__ __align__(16) char smem[65536];
  unsigned short* As = (unsigned short*)smem;            // [2][8192]
  unsigned short* Bs = (unsigned short*)(smem + 32768);  // [2][8192]
  unsigned short* Ct = (unsigned short*)smem;            // [128][136]

  const int bid = blockIdx.x;
  const int tid = threadIdx.x;
  const int w = tid >> 6, l = tid & 63;
  const int wm = w >> 2, wn = w & 3;             // 2x4 wave grid
  const int rA = l & 15, kg = l >> 4;
  const int xr = (rA & 7) << 3;                  // read-side XOR (ushorts)
  const int colsw = ((l & 7) * 8) ^ ((l >> 3) << 3);   // stage-side swizzled col

  const bool proj = bid < 288;
  const unsigned short *A, *B;
  int bm, bn;
  if (proj) {
    int swz = (bid & 7) * 36 + (bid >> 3);       // 288 = 8*36, bijective
    bm = swz / 6; bn = swz % 6;
    A = X + bm * 128 * DD;
    B = Wall + bn * 128 * DD;
  } else {
    bm = bid - 288; bn = 0;
    A = Xs + bm * 128 * DD;
    B = WcT;
  }

  auto STAGE = [&](int buf, int kt) {
    #pragma unroll
    for (int p = 0; p < 2; ++p) {
      int row = p * 64 + w * 8 + (l >> 3);
      gload16(A + row * DD + kt * 64 + colsw,
              &As[buf * 8192 + (p * 64 + w * 8) * 64]);
    }
    #pragma unroll
    for (int p = 0; p < 2; ++p) {
      int row = p * 64 + w * 8 + (l >> 3);
      gload16(B + row * DD + kt * 64 + colsw,
              &Bs[buf * 8192 + (p * 64 + w * 8) * 64]);
    }
  };

  f32x4 acc[4][2] = {};
  STAGE(0, 0);
  int cur = 0;
  for (int kt = 0; kt < DD / 64; ++kt) {
    if (kt + 1 < DD / 64) {
      STAGE(cur ^ 1, kt + 1);
      S_WAIT_VM(4);
    } else {
      S_WAIT_VM(0);
    }
    __builtin_amdgcn_sched_barrier(0);
    __builtin_amdgcn_s_barrier();
    #pragma unroll
    for (int kk = 0; kk < 2; ++kk) {
      bf16x8 a[4], bfr[2];
      #pragma unroll
      for (int mi = 0; mi < 4; ++mi)
        a[mi] = *(const bf16x8*)&As[cur * 8192 + (wm * 64 + mi * 16 + rA) * 64 +
                                    ((kk * 32 + kg * 8) ^ xr)];
      #pragma unroll
      for (int ni = 0; ni < 2; ++ni)
        bfr[ni] = *(const bf16x8*)&Bs[cur * 8192 + (wn * 32 + ni * 16 + rA) * 64 +
                                      ((kk * 32 + kg * 8) ^ xr)];
      #pragma unroll
      for (int mi = 0; mi < 4; ++mi)
        #pragma unroll
        for (int ni = 0; ni < 2; ++ni)
          acc[mi][ni] =
              __builtin_amdgcn_mfma_f32_16x16x32_bf16(a[mi], bfr[ni], acc[mi][ni], 0, 0, 0);
    }
    S_WAIT_LGKM0();
    __builtin_amdgcn_sched_barrier(0);
    __builtin_amdgcn_s_barrier();
    cur ^= 1;
  }

  if (proj) {
    float bias[2];
    #pragma unroll
    for (int ni = 0; ni < 2; ++ni)
      bias[ni] = ball[bn * 128 + wn * 32 + ni * 16 + rA];

    #pragma unroll
    for (int mi = 0; mi < 4; ++mi)
      #pragma unroll
      for (int i = 0; i < 4; ++i) {
        int row = wm * 64 + mi * 16 + kg * 4 + i;
        #pragma unroll
        for (int ni = 0; ni < 2; ++ni)
          Ct[row * 136 + wn * 32 + ni * 16 + rA] = f2bf(acc[mi][ni][i] + bias[ni]);
      }
    __syncthreads();
    #pragma unroll
    for (int pass = 0; pass < 8; ++pass) {
      int row = pass * 16 + (tid >> 5);
      int c = tid & 31;
      ushort4 v = *(const ushort4*)&Ct[row * 136 + c * 4];
      *(ushort4*)&QS[(bm * 128 + row) * PN + bn * 128 + c * 4] = v;
    }
  } else {
    float* o2 = out + (long)NQ * NS;
    #pragma unroll
    for (int mi = 0; mi < 4; ++mi)
      #pragma unroll
      for (int i = 0; i < 4; ++i) {
        int row = bm * 128 + wm * 64 + mi * 16 + kg * 4 + i;
        #pragma unroll
        for (int ni = 0; ni < 2; ++ni) {
          int col = wn * 32 + ni * 16 + rA;
          if (col < CC) o2[row * CC + col] = acc[mi][ni][i] + cb[col];
        }
      }
  }
}

// ---------------------------------------------------------------------------
// norm: in-place per-head-segment L2 normalize; rows<4096 get 1/3 folded.
// ---------------------------------------------------------------------------
__global__ __launch_bounds__(256) void norm_kernel(
    unsigned short* __restrict__ QS)   // [6144][768]
{
  const int wid = blockIdx.x * 4 + (threadIdx.x >> 6);
  const int l = threadIdx.x & 63;
  unsigned short* rowp = QS + wid * PN;
  const float scale = (wid < NQ) ? (1.f / 3.f) : 1.f;

  float v[3][4];
  float ss[3];
  #pragma unroll
  for (int h = 0; h < 3; ++h) {
    ushort4 u = *(const ushort4*)&rowp[h * PP + l * 4];
    v[h][0] = bf2f(u.x); v[h][1] = bf2f(u.y);
    v[h][2] = bf2f(u.z); v[h][3] = bf2f(u.w);
    ss[h] = v[h][0]*v[h][0] + v[h][1]*v[h][1] + v[h][2]*v[h][2] + v[h][3]*v[h][3];
  }
  #pragma unroll
  for (int s = 1; s < 64; s <<= 1) {
    ss[0] += __shfl_xor(ss[0], s);
    ss[1] += __shfl_xor(ss[1], s);
    ss[2] += __shfl_xor(ss[2], s);
  }
  #pragma unroll
  for (int h = 0; h < 3; ++h) {
    float inv = scale / fmaxf(sqrtf(ss[h]), 1e-8f);
    ushort4 o;
    o.x = f2bf(v[h][0] * inv); o.y = f2bf(v[h][1] * inv);
    o.z = f2bf(v[h][2] * inv); o.w = f2bf(v[h][3] * inv);
    *(ushort4*)&rowp[h * PP + l * 4] = o;
  }
}

// ---------------------------------------------------------------------------
// mm: EXACTLY 512 blocks = match_scores = Qn @ Sn^T [4096][2048] f32.
//     2 blocks/CU residency * 256 CU = 512 -> zero tail.
//     512 thr / 8 waves, T2 swizzle + counted-vmcnt, LDS f32x4 epilogue.
// ---------------------------------------------------------------------------
__global__ __launch_bounds__(512) void mm_kernel(
    const unsigned short* __restrict__ Qn,
    const unsigned short* __restrict__ Sn,
    float* __restrict__ out)
{
  __shared__ __align__(16) char smem[128 * 132 * 4];
  unsigned short* As = (unsigned short*)smem;            // [2][8192]
  unsigned short* Bs = (unsigned short*)(smem + 32768);  // [2][8192]
  float* Ct = (float*)smem;                              // [128][132]

  const int bid = blockIdx.x;
  const int tid = threadIdx.x;
  const int w = tid >> 6, l = tid & 63;
  const int wm = w >> 2, wn = w & 3;             // 2x4 wave grid
  const int rA = l & 15, kg = l >> 4;
  const int xr = (rA & 7) << 3;
  const int colsw = ((l & 7) * 8) ^ ((l >> 3) << 3);

  // XCD-chunk swizzle: xcd gets bm in [xcd*4, xcd*4+4) x all 16 bn (~3.8MiB/L2)
  const int xcd = bid & 7, idx = bid >> 3;
  const int bm = xcd * 4 + (idx & 3);
  const int bn = idx >> 2;
  const unsigned short* A = Qn + bm * 128 * PN;
  const unsigned short* B = Sn + bn * 128 * PN;

  auto STAGE = [&](int buf, int kt) {
    #pragma unroll
    for (int p = 0; p < 2; ++p) {
      int row = p * 64 + w * 8 + (l >> 3);
      gload16(A + row * PN + kt * 64 + colsw,
              &As[buf * 8192 + (p * 64 + w * 8) * 64]);
    }
    #pragma unroll
    for (int p = 0; p < 2; ++p) {
      int row = p * 64 + w * 8 + (l >> 3);
      gload16(B + row * PN + kt * 64 + colsw,
              &Bs[buf * 8192 + (p * 64 + w * 8) * 64]);
    }
  };

  f32x4 acc[4][2] = {};
  STAGE(0, 0);
  int cur = 0;
  for (int kt = 0; kt < PN / 64; ++kt) {
    if (kt + 1 < PN / 64) {
      STAGE(cur ^ 1, kt + 1);
      S_WAIT_VM(4);
    } else {
      S_WAIT_VM(0);
    }
    __builtin_amdgcn_sched_barrier(0);
    __builtin_amdgcn_s_barrier();
    #pragma unroll
    for (int kk = 0; kk < 2; ++kk) {
      bf16x8 a[4], bfr[2];
      #pragma unroll
      for (int mi = 0; mi < 4; ++mi)
        a[mi] = *(const bf16x8*)&As[cur * 8192 + (wm * 64 + mi * 16 + rA) * 64 +
                                    ((kk * 32 + kg * 8) ^ xr)];
      #pragma unroll
      for (int ni = 0; ni < 2; ++ni)
        bfr[ni] = *(const bf16x8*)&Bs[cur * 8192 + (wn * 32 + ni * 16 + rA) * 64 +
                                      ((kk * 32 + kg * 8) ^ xr)];
      #pragma unroll
      for (int mi = 0; mi < 4; ++mi)
        #pragma unroll
        for (int ni = 0; ni < 2; ++ni)
          acc[mi][ni] =
              __builtin_amdgcn_mfma_f32_16x16x32_bf16(a[mi], bfr[ni], acc[mi][ni], 0, 0, 0);
    }
    S_WAIT_LGKM0();
    __builtin_amdgcn_sched_barrier(0);
    __builtin_amdgcn_s_barrier();
    cur ^= 1;
  }

  #pragma unroll
  for (int mi = 0; mi < 4; ++mi)
    #pragma unroll
    for (int i = 0; i < 4; ++i) {
      int row = wm * 64 + mi * 16 + kg * 4 + i;
      #pragma unroll
      for (int ni = 0; ni < 2; ++ni)
        Ct[row * 132 + wn * 32 + ni * 16 + rA] = acc[mi][ni][i];
    }
  __syncthreads();
  #pragma unroll
  for (int pass = 0; pass < 8; ++pass) {
    int row = pass * 16 + (tid >> 5);
    int c = tid & 31;
    f32x4 v = *(const f32x4*)&Ct[row * 132 + c * 4];
    *(f32x4*)&out[(long)(bm * 128 + row) * NS + bn * 128 + c * 4] = v;
  }
}

// ---------------------------------------------------------------------------
extern "C" void kernel_launch(void* const* d_in, const int* in_sizes, int n_in,
                              void* d_out, int out_size, void* d_ws, size_t ws_size,
                              hipStream_t stream) {
  const float* q   = (const float*)d_in[0];
  const float* sup = (const float*)d_in[1];
  const float* hW  = (const float*)d_in[2];
  const float* hb  = (const float*)d_in[3];
  const float* cW  = (const float*)d_in[4];
  const float* cb  = (const float*)d_in[5];
  float* out = (float*)d_out;

  char* ws = (char*)d_ws;
  unsigned short* Xq  = (unsigned short*)(ws + 0);                      // 8 MiB  [4096][1024]
  unsigned short* Xs  = (unsigned short*)(ws + (8u  << 20));            // 4 MiB  [2048][1024]
  unsigned short* Wt  = (unsigned short*)(ws + (12u << 20));            // 1.5 MiB [768][1024]
  unsigned short* WcT = (unsigned short*)(ws + (12u << 20) + 1572864u); // 256 KiB [128][1024]
  unsigned short* QS  = (unsigned short*)(ws + (14u << 20));            // 9 MiB  [6144][768]
  unsigned short* Qn  = QS;
  unsigned short* Sn  = QS + (size_t)NQ * PN;

  prep_kernel<<<1760, 256, 0, stream>>>(q, sup, hW, cW, Xq, Xs, Wt, WcT);
  pgemm_kernel<<<304, 512, 0, stream>>>(Xq, Wt, hb, Xs, WcT, cb, QS, out);
  norm_kernel<<<NR / 4, 256, 0, stream>>>(QS);
  mm_kernel<<<512, 512, 0, stream>>>(Qn, Sn, out);
}

// Round 10
// 155.538 us; speedup vs baseline: 1.2926x; 1.0362x over previous
//
#include <hip/hip_runtime.h>

#define NQ 4096
#define NS 2048
#define DD 1024
#define HH 3
#define PP 256
#define CC 100
#define NR (NQ + NS)        // 6144 projected rows
#define PN (HH * PP)        // 768 projected cols

typedef __attribute__((ext_vector_type(8))) short bf16x8;
typedef __attribute__((ext_vector_type(4))) float f32x4;

#define AS1 __attribute__((address_space(1)))
#define AS3 __attribute__((address_space(3)))

#define S_WAIT_VM(n) asm volatile("s_waitcnt vmcnt(" #n ")" ::: "memory")
#define S_WAIT_LGKM0() asm volatile("s_waitcnt lgkmcnt(0)" ::: "memory")

__device__ __forceinline__ void gload16(const void* g, void* l) {
  __builtin_amdgcn_global_load_lds((const AS1 unsigned int*)g,
                                   (AS3 unsigned int*)l, 16, 0, 0);
}

__device__ __forceinline__ unsigned short f2bf(float f) {
  union { float f; unsigned u; } v; v.f = f;
  return (unsigned short)((v.u + 0x7FFFu + ((v.u >> 16) & 1u)) >> 16);
}

__device__ __forceinline__ float bf2f(unsigned short s) {
  union { unsigned u; float f; } v; v.u = ((unsigned)s) << 16;
  return v.f;
}

// ---------------------------------------------------------------------------
// prep: blocks 0..223     transpose tiles (192 hW + 32 cW)  [FIRST: pgemm dep]
//       blocks 224..1247  query mean -> Xq bf16
//       blocks 1248..1759 support cast -> Xs bf16
// ---------------------------------------------------------------------------
__global__ __launch_bounds__(256) void prep_kernel(
    const float* __restrict__ q,      // [4][4096][1024]
    const float* __restrict__ sup,    // [2048][1024]
    const float* __restrict__ hW,     // [3][1024][256]
    const float* __restrict__ cW,     // [1024][100]
    unsigned short* __restrict__ Xq,  // [4096][1024]
    unsigned short* __restrict__ Xs,  // [2048][1024]
    unsigned short* __restrict__ Wt,  // [3][256][1024]
    unsigned short* __restrict__ WcT) // [128][1024]
{
  __shared__ unsigned short T[64][72];
  const int b = blockIdx.x, t = threadIdx.x;

  if (b >= 224) {
    if (b < 1248) {
      int bq = b - 224;
      #pragma unroll
      for (int i = 0; i < 4; ++i) {
        int idx = (bq * 1024 + i * 256 + t) * 4;
        const float4 a  = *(const float4*)&q[idx];
        const float4 c1 = *(const float4*)&q[NQ * DD + idx];
        const float4 c2 = *(const float4*)&q[2 * NQ * DD + idx];
        const float4 c3 = *(const float4*)&q[3 * NQ * DD + idx];
        ushort4 o;
        o.x = f2bf((a.x + c1.x + c2.x + c3.x) * 0.25f);
        o.y = f2bf((a.y + c1.y + c2.y + c3.y) * 0.25f);
        o.z = f2bf((a.z + c1.z + c2.z + c3.z) * 0.25f);
        o.w = f2bf((a.w + c1.w + c2.w + c3.w) * 0.25f);
        *(ushort4*)&Xq[idx] = o;
      }
    } else {
      int bs = b - 1248;
      #pragma unroll
      for (int i = 0; i < 4; ++i) {
        int idx = (bs * 1024 + i * 256 + t) * 4;
        const float4 a = *(const float4*)&sup[idx];
        ushort4 o;
        o.x = f2bf(a.x); o.y = f2bf(a.y); o.z = f2bf(a.z); o.w = f2bf(a.w);
        *(ushort4*)&Xs[idx] = o;
      }
    }
    return;
  }

  const float* src; unsigned short* dst; int srcC, pvalid, k0, p0;
  if (b < 192) {
    int r = b; int h = r / 64; int rr = r % 64;
    k0 = (rr >> 2) * 64; p0 = (rr & 3) * 64;
    src = hW + h * DD * PP; srcC = PP; pvalid = PP;
    dst = Wt + (h * PP + p0) * DD;
  } else {
    int r = b - 192;
    k0 = (r >> 1) * 64; p0 = (r & 1) * 64;
    src = cW; srcC = CC; pvalid = CC;
    dst = WcT + p0 * DD;
  }
  {
    int kl = t >> 2, pb = (t & 3) * 4;
    #pragma unroll
    for (int j = 0; j < 4; ++j) {
      int pl = pb + j * 16;
      int p = p0 + pl;
      float4 v; v.x = v.y = v.z = v.w = 0.f;
      if (p + 3 < pvalid) {
        v = *(const float4*)&src[(k0 + kl) * srcC + p];
      } else {
        if (p + 0 < pvalid) v.x = src[(k0 + kl) * srcC + p + 0];
        if (p + 1 < pvalid) v.y = src[(k0 + kl) * srcC + p + 1];
        if (p + 2 < pvalid) v.z = src[(k0 + kl) * srcC + p + 2];
        if (p + 3 < pvalid) v.w = src[(k0 + kl) * srcC + p + 3];
      }
      T[kl][pl + 0] = f2bf(v.x); T[kl][pl + 1] = f2bf(v.y);
      T[kl][pl + 2] = f2bf(v.z); T[kl][pl + 3] = f2bf(v.w);
    }
    __syncthreads();
    int pr = t >> 2, kb = (t & 3) * 4;
    #pragma unroll
    for (int j = 0; j < 4; ++j) {
      int kk = kb + j * 16;
      ushort4 o;
      o.x = T[kk + 0][pr]; o.y = T[kk + 1][pr];
      o.z = T[kk + 2][pr]; o.w = T[kk + 3][pr];
      *(ushort4*)&dst[pr * DD + k0 + kk] = o;
    }
  }
}

// ---------------------------------------------------------------------------
// pgemm: blocks 0..287   QS[6144][768] = bf16( X @ Wall^T + b )
//        blocks 288..303 support_preds = Xs @ WcT^T + cb -> out (f32)
//        128x128, BK=64, 512 thr / 8 waves (2x4), T2 swizzle, counted vmcnt.
// ---------------------------------------------------------------------------
__global__ __launch_bounds__(512) void pgemm_kernel(
    const unsigned short* __restrict__ X,    // [6144][1024] (Xq||Xs)
    const unsigned short* __restrict__ Wall, // [768][1024]
    const float* __restrict__ ball,          // [768]
    const unsigned short* __restrict__ Xs,   // [2048][1024]
    const unsigned short* __restrict__ WcT,  // [128][1024]
    const float* __restrict__ cb,            // [100]
    unsigned short* __restrict__ QS,         // [6144][768]
    float* __restrict__ out)                 // preds at out + NQ*NS
{
  __shared__ __align__(16) char smem[65536];
  unsigned short* As = (unsigned short*)smem;            // [2][8192]
  unsigned short* Bs = (unsigned short*)(smem + 32768);  // [2][8192]
  unsigned short* Ct = (unsigned short*)smem;            // [128][136]

  const int bid = blockIdx.x;
  const int tid = threadIdx.x;
  const int w = tid >> 6, l = tid & 63;
  const int wm = w >> 2, wn = w & 3;             // 2x4 wave grid
  const int rA = l & 15, kg = l >> 4;
  const int xr = (rA & 7) << 3;                  // read-side XOR (ushorts)
  const int colsw = ((l & 7) * 8) ^ ((l >> 3) << 3);   // stage-side swizzled col

  const bool proj = bid < 288;
  const unsigned short *A, *B;
  int bm, bn;
  if (proj) {
    int swz = (bid & 7) * 36 + (bid >> 3);       // 288 = 8*36, bijective
    bm = swz / 6; bn = swz % 6;
    A = X + bm * 128 * DD;
    B = Wall + bn * 128 * DD;
  } else {
    bm = bid - 288; bn = 0;
    A = Xs + bm * 128 * DD;
    B = WcT;
  }

  auto STAGE = [&](int buf, int kt) {
    #pragma unroll
    for (int p = 0; p < 2; ++p) {
      int row = p * 64 + w * 8 + (l >> 3);
      gload16(A + row * DD + kt * 64 + colsw,
              &As[buf * 8192 + (p * 64 + w * 8) * 64]);
    }
    #pragma unroll
    for (int p = 0; p < 2; ++p) {
      int row = p * 64 + w * 8 + (l >> 3);
      gload16(B + row * DD + kt * 64 + colsw,
              &Bs[buf * 8192 + (p * 64 + w * 8) * 64]);
    }
  };

  f32x4 acc[4][2] = {};
  STAGE(0, 0);
  int cur = 0;
  for (int kt = 0; kt < DD / 64; ++kt) {
    if (kt + 1 < DD / 64) {
      STAGE(cur ^ 1, kt + 1);
      S_WAIT_VM(4);
    } else {
      S_WAIT_VM(0);
    }
    __builtin_amdgcn_sched_barrier(0);
    __builtin_amdgcn_s_barrier();
    #pragma unroll
    for (int kk = 0; kk < 2; ++kk) {
      bf16x8 a[4], bfr[2];
      #pragma unroll
      for (int mi = 0; mi < 4; ++mi)
        a[mi] = *(const bf16x8*)&As[cur * 8192 + (wm * 64 + mi * 16 + rA) * 64 +
                                    ((kk * 32 + kg * 8) ^ xr)];
      #pragma unroll
      for (int ni = 0; ni < 2; ++ni)
        bfr[ni] = *(const bf16x8*)&Bs[cur * 8192 + (wn * 32 + ni * 16 + rA) * 64 +
                                      ((kk * 32 + kg * 8) ^ xr)];
      #pragma unroll
      for (int mi = 0; mi < 4; ++mi)
        #pragma unroll
        for (int ni = 0; ni < 2; ++ni)
          acc[mi][ni] =
              __builtin_amdgcn_mfma_f32_16x16x32_bf16(a[mi], bfr[ni], acc[mi][ni], 0, 0, 0);
    }
    S_WAIT_LGKM0();
    __builtin_amdgcn_sched_barrier(0);
    __builtin_amdgcn_s_barrier();
    cur ^= 1;
  }

  if (proj) {
    float bias[2];
    #pragma unroll
    for (int ni = 0; ni < 2; ++ni)
      bias[ni] = ball[bn * 128 + wn * 32 + ni * 16 + rA];

    #pragma unroll
    for (int mi = 0; mi < 4; ++mi)
      #pragma unroll
      for (int i = 0; i < 4; ++i) {
        int row = wm * 64 + mi * 16 + kg * 4 + i;
        #pragma unroll
        for (int ni = 0; ni < 2; ++ni)
          Ct[row * 136 + wn * 32 + ni * 16 + rA] = f2bf(acc[mi][ni][i] + bias[ni]);
      }
    __syncthreads();
    #pragma unroll
    for (int pass = 0; pass < 8; ++pass) {
      int row = pass * 16 + (tid >> 5);
      int c = tid & 31;
      ushort4 v = *(const ushort4*)&Ct[row * 136 + c * 4];
      *(ushort4*)&QS[(bm * 128 + row) * PN + bn * 128 + c * 4] = v;
    }
  } else {
    float* o2 = out + (long)NQ * NS;
    #pragma unroll
    for (int mi = 0; mi < 4; ++mi)
      #pragma unroll
      for (int i = 0; i < 4; ++i) {
        int row = bm * 128 + wm * 64 + mi * 16 + kg * 4 + i;
        #pragma unroll
        for (int ni = 0; ni < 2; ++ni) {
          int col = wn * 32 + ni * 16 + rA;
          if (col < CC) o2[row * CC + col] = acc[mi][ni][i] + cb[col];
        }
      }
  }
}

// ---------------------------------------------------------------------------
// norm: in-place per-head-segment L2 normalize; rows<4096 get 1/3 folded.
// ---------------------------------------------------------------------------
__global__ __launch_bounds__(256) void norm_kernel(
    unsigned short* __restrict__ QS)   // [6144][768]
{
  const int wid = blockIdx.x * 4 + (threadIdx.x >> 6);
  const int l = threadIdx.x & 63;
  unsigned short* rowp = QS + wid * PN;
  const float scale = (wid < NQ) ? (1.f / 3.f) : 1.f;

  float v[3][4];
  float ss[3];
  #pragma unroll
  for (int h = 0; h < 3; ++h) {
    ushort4 u = *(const ushort4*)&rowp[h * PP + l * 4];
    v[h][0] = bf2f(u.x); v[h][1] = bf2f(u.y);
    v[h][2] = bf2f(u.z); v[h][3] = bf2f(u.w);
    ss[h] = v[h][0]*v[h][0] + v[h][1]*v[h][1] + v[h][2]*v[h][2] + v[h][3]*v[h][3];
  }
  #pragma unroll
  for (int s = 1; s < 64; s <<= 1) {
    ss[0] += __shfl_xor(ss[0], s);
    ss[1] += __shfl_xor(ss[1], s);
    ss[2] += __shfl_xor(ss[2], s);
  }
  #pragma unroll
  for (int h = 0; h < 3; ++h) {
    float inv = scale / fmaxf(sqrtf(ss[h]), 1e-8f);
    ushort4 o;
    o.x = f2bf(v[h][0] * inv); o.y = f2bf(v[h][1] * inv);
    o.z = f2bf(v[h][2] * inv); o.w = f2bf(v[h][3] * inv);
    *(ushort4*)&rowp[h * PP + l * 4] = o;
  }
}

// ---------------------------------------------------------------------------
// mm: EXACTLY 512 blocks = match_scores = Qn @ Sn^T [4096][2048] f32.
//     512 thr / 8 waves, T2 swizzle + counted-vmcnt, LDS f32x4 epilogue.
// ---------------------------------------------------------------------------
__global__ __launch_bounds__(512) void mm_kernel(
    const unsigned short* __restrict__ Qn,
    const unsigned short* __restrict__ Sn,
    float* __restrict__ out)
{
  __shared__ __align__(16) char smem[128 * 132 * 4];
  unsigned short* As = (unsigned short*)smem;            // [2][8192]
  unsigned short* Bs = (unsigned short*)(smem + 32768);  // [2][8192]
  float* Ct = (float*)smem;                              // [128][132]

  const int bid = blockIdx.x;
  const int tid = threadIdx.x;
  const int w = tid >> 6, l = tid & 63;
  const int wm = w >> 2, wn = w & 3;             // 2x4 wave grid
  const int rA = l & 15, kg = l >> 4;
  const int xr = (rA & 7) << 3;
  const int colsw = ((l & 7) * 8) ^ ((l >> 3) << 3);

  // XCD-chunk swizzle: xcd gets bm in [xcd*4, xcd*4+4) x all 16 bn (~3.8MiB/L2)
  const int xcd = bid & 7, idx = bid >> 3;
  const int bm = xcd * 4 + (idx & 3);
  const int bn = idx >> 2;
  const unsigned short* A = Qn + bm * 128 * PN;
  const unsigned short* B = Sn + bn * 128 * PN;

  auto STAGE = [&](int buf, int kt) {
    #pragma unroll
    for (int p = 0; p < 2; ++p) {
      int row = p * 64 + w * 8 + (l >> 3);
      gload16(A + row * PN + kt * 64 + colsw,
              &As[buf * 8192 + (p * 64 + w * 8) * 64]);
    }
    #pragma unroll
    for (int p = 0; p < 2; ++p) {
      int row = p * 64 + w * 8 + (l >> 3);
      gload16(B + row * PN + kt * 64 + colsw,
              &Bs[buf * 8192 + (p * 64 + w * 8) * 64]);
    }
  };

  f32x4 acc[4][2] = {};
  STAGE(0, 0);
  int cur = 0;
  for (int kt = 0; kt < PN / 64; ++kt) {
    if (kt + 1 < PN / 64) {
      STAGE(cur ^ 1, kt + 1);
      S_WAIT_VM(4);
    } else {
      S_WAIT_VM(0);
    }
    __builtin_amdgcn_sched_barrier(0);
    __builtin_amdgcn_s_barrier();
    #pragma unroll
    for (int kk = 0; kk < 2; ++kk) {
      bf16x8 a[4], bfr[2];
      #pragma unroll
      for (int mi = 0; mi < 4; ++mi)
        a[mi] = *(const bf16x8*)&As[cur * 8192 + (wm * 64 + mi * 16 + rA) * 64 +
                                    ((kk * 32 + kg * 8) ^ xr)];
      #pragma unroll
      for (int ni = 0; ni < 2; ++ni)
        bfr[ni] = *(const bf16x8*)&Bs[cur * 8192 + (wn * 32 + ni * 16 + rA) * 64 +
                                      ((kk * 32 + kg * 8) ^ xr)];
      #pragma unroll
      for (int mi = 0; mi < 4; ++mi)
        #pragma unroll
        for (int ni = 0; ni < 2; ++ni)
          acc[mi][ni] =
              __builtin_amdgcn_mfma_f32_16x16x32_bf16(a[mi], bfr[ni], acc[mi][ni], 0, 0, 0);
    }
    S_WAIT_LGKM0();
    __builtin_amdgcn_sched_barrier(0);
    __builtin_amdgcn_s_barrier();
    cur ^= 1;
  }

  #pragma unroll
  for (int mi = 0; mi < 4; ++mi)
    #pragma unroll
    for (int i = 0; i < 4; ++i) {
      int row = wm * 64 + mi * 16 + kg * 4 + i;
      #pragma unroll
      for (int ni = 0; ni < 2; ++ni)
        Ct[row * 132 + wn * 32 + ni * 16 + rA] = acc[mi][ni][i];
    }
  __syncthreads();
  #pragma unroll
  for (int pass = 0; pass < 8; ++pass) {
    int row = pass * 16 + (tid >> 5);
    int c = tid & 31;
    f32x4 v = *(const f32x4*)&Ct[row * 132 + c * 4];
    *(f32x4*)&out[(long)(bm * 128 + row) * NS + bn * 128 + c * 4] = v;
  }
}

// ---------------------------------------------------------------------------
extern "C" void kernel_launch(void* const* d_in, const int* in_sizes, int n_in,
                              void* d_out, int out_size, void* d_ws, size_t ws_size,
                              hipStream_t stream) {
  const float* q   = (const float*)d_in[0];
  const float* sup = (const float*)d_in[1];
  const float* hW  = (const float*)d_in[2];
  const float* hb  = (const float*)d_in[3];
  const float* cW  = (const float*)d_in[4];
  const float* cb  = (const float*)d_in[5];
  float* out = (float*)d_out;

  char* ws = (char*)d_ws;
  unsigned short* Xq  = (unsigned short*)(ws + 0);                      // 8 MiB  [4096][1024]
  unsigned short* Xs  = (unsigned short*)(ws + (8u  << 20));            // 4 MiB  [2048][1024]
  unsigned short* Wt  = (unsigned short*)(ws + (12u << 20));            // 1.5 MiB [768][1024]
  unsigned short* WcT = (unsigned short*)(ws + (12u << 20) + 1572864u); // 256 KiB [128][1024]
  unsigned short* QS  = (unsigned short*)(ws + (14u << 20));            // 9 MiB  [6144][768]
  unsigned short* Qn  = QS;
  unsigned short* Sn  = QS + (size_t)NQ * PN;

  prep_kernel<<<1760, 256, 0, stream>>>(q, sup, hW, cW, Xq, Xs, Wt, WcT);
  pgemm_kernel<<<304, 512, 0, stream>>>(Xq, Wt, hb, Xs, WcT, cb, QS, out);
  norm_kernel<<<NR / 4, 256, 0, stream>>>(QS);
  mm_kernel<<<512, 512, 0, stream>>>(Qn, Sn, out);
}